// Round 4
// baseline (748.418 us; speedup 1.0000x reference)
//
#include <hip/hip_runtime.h>
#include <hip/hip_bf16.h>
#include <math.h>

#define B_DIM 4096
#define D_IN  2048
#define D_HID 3584
#define D_OUT 2048

typedef __bf16 bf16;
typedef float  floatx4  __attribute__((ext_vector_type(4)));
typedef float  floatx16 __attribute__((ext_vector_type(16)));
typedef bf16   bf16x8   __attribute__((ext_vector_type(8)));

typedef __attribute__((address_space(1))) const void* gptr1;
typedef __attribute__((address_space(3))) void*       lptr3;

__device__ __forceinline__ void load_lds16(const void* g, void* l) {
    __builtin_amdgcn_global_load_lds((gptr1)g, (lptr3)l, 16, 0, 0);
}

struct HL { bf16 h, l; };
__device__ __forceinline__ HL split2(float v) {
    HL r;
    r.h = (bf16)v;
    r.l = (bf16)(v - (float)r.h);
    return r;
}

// ---------------------------------------------------------------------------
// Vesica (fp32 in): x_overlap = x * (1 + relu(1 - |dist - 1|)); emit bf16 hi/lo
// ---------------------------------------------------------------------------
__global__ __launch_bounds__(256) void vesica_kernel(const float* __restrict__ x,
                                                     bf16* __restrict__ xh,
                                                     bf16* __restrict__ xl) {
    const int b  = blockIdx.x;
    const int bp = (b == 0) ? (B_DIM - 1) : (b - 1);
    const int t  = threadIdx.x;

    const floatx4* xr = (const floatx4*)(x + (size_t)b  * D_IN);
    const floatx4* pr = (const floatx4*)(x + (size_t)bp * D_IN);
    const floatx4 v0 = xr[t * 2], v1 = xr[t * 2 + 1];
    const floatx4 p0 = pr[t * 2], p1 = pr[t * 2 + 1];

    float s = 0.f;
#pragma unroll
    for (int j = 0; j < 4; ++j) {
        const float d0 = v0[j] - p0[j], d1 = v1[j] - p1[j];
        s += d0 * d0 + d1 * d1;
    }
#pragma unroll
    for (int off = 32; off > 0; off >>= 1) s += __shfl_down(s, off, 64);

    __shared__ float red[4];
    const int wave = t >> 6, lane = t & 63;
    if (lane == 0) red[wave] = s;
    __syncthreads();
    const float dist = sqrtf(red[0] + red[1] + red[2] + red[3]);
    const float sc   = 1.f + fmaxf(0.f, 1.f - fabsf(dist - 1.f));

    bf16x8 h, l;
#pragma unroll
    for (int j = 0; j < 4; ++j) {
        const HL a  = split2(v0[j] * sc);
        const HL b2 = split2(v1[j] * sc);
        h[j] = a.h;      l[j] = a.l;
        h[4 + j] = b2.h; l[4 + j] = b2.l;
    }
    ((bf16x8*)(xh + (size_t)b * D_IN))[t] = h;
    ((bf16x8*)(xl + (size_t)b * D_IN))[t] = l;
}

// ---------------------------------------------------------------------------
// Split fp32 weight array into bf16 hi/lo.
// ---------------------------------------------------------------------------
__global__ __launch_bounds__(256) void split_kernel(const float* __restrict__ w,
                                                    bf16* __restrict__ wh,
                                                    bf16* __restrict__ wl) {
    const size_t i = (size_t)blockIdx.x * 256 + threadIdx.x;
    const floatx4 a = ((const floatx4*)w)[i * 2];
    const floatx4 b = ((const floatx4*)w)[i * 2 + 1];
    bf16x8 h, l;
#pragma unroll
    for (int j = 0; j < 4; ++j) {
        const HL u = split2(a[j]);
        const HL v = split2(b[j]);
        h[j] = u.h;     l[j] = u.l;
        h[4 + j] = v.h; l[4 + j] = v.l;
    }
    ((bf16x8*)wh)[i] = h;
    ((bf16x8*)wl)[i] = l;
}

// ---------------------------------------------------------------------------
// Flip W_female [2048,3584] along axis 1, split into bf16 hi/lo.
// ---------------------------------------------------------------------------
__global__ __launch_bounds__(256) void flipsplit_kernel(const float* __restrict__ w,
                                                        bf16* __restrict__ wh,
                                                        bf16* __restrict__ wl) {
    const int i = blockIdx.x * 256 + threadIdx.x;
    const int o = i / 448;
    const int g = i - o * 448;
    const float* src = w + (size_t)o * 3584 + (size_t)(447 - g) * 8;
    const floatx4 a = ((const floatx4*)src)[0];
    const floatx4 b = ((const floatx4*)src)[1];
    bf16x8 h, l;
#pragma unroll
    for (int j = 0; j < 4; ++j) {
        const HL u = split2(b[3 - j]);   // out[0..3] = src[7..4]
        const HL v = split2(a[3 - j]);   // out[4..7] = src[3..0]
        h[j] = u.h;     l[j] = u.l;
        h[4 + j] = v.h; l[4 + j] = v.l;
    }
    ((bf16x8*)wh)[(size_t)o * 448 + g] = h;
    ((bf16x8*)wl)[(size_t)o * 448 + g] = l;
}

// ---------------------------------------------------------------------------
// bf16x3 split-precision GEMM  C[M,N] = A[M,K] * B[N,K]^T
//   C ≈ Ah·Bh + Al·Bh + Ah·Bl  (fp32 accumulate) — ~17 mantissa bits
// 128x128 tile, BK=32, 4 waves (2x2), each wave 2x2 of 32x32x16 bf16 MFMAs.
// A-frag: A[m=lane&31][k=(lane>>5)*8+j]; C/D: col=lane&31,
// row=(reg&3)+8*(reg>>2)+4*(lane>>5)  [m74/m101-verified]
// OUT_MODE 1: flower — phase multiply, write bf16 hi/lo (C0/C1)
// OUT_MODE 2: write fp32 to C0
// ---------------------------------------------------------------------------
template <int OUT_MODE>
__global__ __launch_bounds__(256) void gemm3_bt(const bf16* __restrict__ Ah,
                                                const bf16* __restrict__ Al,
                                                const bf16* __restrict__ Bh,
                                                const bf16* __restrict__ Bl,
                                                void* __restrict__ C0,
                                                void* __restrict__ C1,
                                                int M, int N, int K) {
    __shared__ bf16 sAh[128 * 32];
    __shared__ bf16 sAl[128 * 32];
    __shared__ bf16 sBh[128 * 32];
    __shared__ bf16 sBl[128 * 32];

    const int tid  = threadIdx.x;
    const int wave = tid >> 6;
    const int lane = tid & 63;
    const int m0   = blockIdx.y * 128;
    const int n0   = blockIdx.x * 128;
    const int wm   = wave & 1;
    const int wn   = wave >> 1;

    floatx16 acc[2][2];
#pragma unroll
    for (int i = 0; i < 2; ++i)
#pragma unroll
        for (int j = 0; j < 2; ++j)
#pragma unroll
            for (int r = 0; r < 16; ++r) acc[i][j][r] = 0.f;

    const int lr = lane & 31;          // row within 32x32 fragment
    const int lk = (lane >> 5) << 3;   // k offset (0 or 8) of the 8-elem frag

    for (int kt = 0; kt < K; kt += 32) {
#pragma unroll
        for (int i = 0; i < 2; ++i) {
            const int e   = ((i * 4 + wave) << 9) + (lane << 3);
            const int row = e >> 5;
            const int col = e & 31;
            const size_t ga = (size_t)(m0 + row) * K + kt + col;
            const size_t gb = (size_t)(n0 + row) * K + kt + col;
            load_lds16(&Ah[ga], &sAh[e]);
            load_lds16(&Al[ga], &sAl[e]);
            load_lds16(&Bh[gb], &sBh[e]);
            load_lds16(&Bl[gb], &sBl[e]);
        }
        __syncthreads();

#pragma unroll
        for (int ks = 0; ks < 2; ++ks) {
            const int ko = ks * 16 + lk;
            bf16x8 ah[2], al[2], bh[2], bl[2];
#pragma unroll
            for (int mi = 0; mi < 2; ++mi) {
                const int off = ((wm * 64 + mi * 32 + lr) << 5) + ko;
                ah[mi] = *(const bf16x8*)&sAh[off];
                al[mi] = *(const bf16x8*)&sAl[off];
            }
#pragma unroll
            for (int ni = 0; ni < 2; ++ni) {
                const int off = ((wn * 64 + ni * 32 + lr) << 5) + ko;
                bh[ni] = *(const bf16x8*)&sBh[off];
                bl[ni] = *(const bf16x8*)&sBl[off];
            }
#pragma unroll
            for (int mi = 0; mi < 2; ++mi)
#pragma unroll
                for (int ni = 0; ni < 2; ++ni) {
                    acc[mi][ni] = __builtin_amdgcn_mfma_f32_32x32x16_bf16(
                        ah[mi], bh[ni], acc[mi][ni], 0, 0, 0);
                    acc[mi][ni] = __builtin_amdgcn_mfma_f32_32x32x16_bf16(
                        al[mi], bh[ni], acc[mi][ni], 0, 0, 0);
                    acc[mi][ni] = __builtin_amdgcn_mfma_f32_32x32x16_bf16(
                        ah[mi], bl[ni], acc[mi][ni], 0, 0, 0);
                }
        }
        __syncthreads();
    }

    // epilogue: 32x32 C/D layout col=lane&31, row=(r&3)+8*(r>>2)+4*(lane>>5)
    const int cl = lane & 31;
    const int rb = (lane >> 5) << 2;
#pragma unroll
    for (int mi = 0; mi < 2; ++mi) {
#pragma unroll
        for (int ni = 0; ni < 2; ++ni) {
            const int col = n0 + wn * 64 + ni * 32 + cl;
            float pm = 1.0f;
            if (OUT_MODE == 1) {
                const int jm = col & 511;
                if (jm < 2) {
                    const float ph = 0.8975979010256552f * (float)(col >> 9); // 2pi/7*c
                    pm = (jm == 0) ? cosf(ph) : sinf(ph);
                }
            }
#pragma unroll
            for (int r = 0; r < 16; ++r) {
                const int row = m0 + wm * 64 + mi * 32 + (r & 3) + 8 * (r >> 2) + rb;
                const size_t idx = (size_t)row * N + col;
                float v = acc[mi][ni][r];
                if (OUT_MODE == 1) {
                    v *= pm;
                    const HL u = split2(v);
                    ((bf16*)C0)[idx] = u.h;
                    ((bf16*)C1)[idx] = u.l;
                } else {
                    ((float*)C0)[idx] = v;
                }
            }
        }
    }
}

// ---------------------------------------------------------------------------
// Combine: phase_lock = sigmoid(male . female); out = pl*male + (1-pl)*female
// ---------------------------------------------------------------------------
__global__ __launch_bounds__(256) void combine_kernel(const float* __restrict__ male,
                                                      const float* __restrict__ female,
                                                      float* __restrict__ out) {
    const int b = blockIdx.x;
    const int t = threadIdx.x;

    const floatx4* m4 = (const floatx4*)(male   + (size_t)b * D_OUT);
    const floatx4* f4 = (const floatx4*)(female + (size_t)b * D_OUT);
    const floatx4 mv0 = m4[t * 2], mv1 = m4[t * 2 + 1];
    const floatx4 fv0 = f4[t * 2], fv1 = f4[t * 2 + 1];

    float s = 0.f;
#pragma unroll
    for (int j = 0; j < 4; ++j) s += mv0[j] * fv0[j] + mv1[j] * fv1[j];
#pragma unroll
    for (int off = 32; off > 0; off >>= 1) s += __shfl_down(s, off, 64);

    __shared__ float red[4];
    const int wave = t >> 6, lane = t & 63;
    if (lane == 0) red[wave] = s;
    __syncthreads();
    const float dot = red[0] + red[1] + red[2] + red[3];
    const float pl  = 1.f / (1.f + expf(-dot));

    floatx4 o0, o1;
#pragma unroll
    for (int j = 0; j < 4; ++j) {
        o0[j] = pl * mv0[j] + (1.f - pl) * fv0[j];
        o1[j] = pl * mv1[j] + (1.f - pl) * fv1[j];
    }
    floatx4* o4 = (floatx4*)(out + (size_t)b * D_OUT);
    o4[t * 2]     = o0;
    o4[t * 2 + 1] = o1;
}

// ---------------------------------------------------------------------------
extern "C" void kernel_launch(void* const* d_in, const int* in_sizes, int n_in,
                              void* d_out, int out_size, void* d_ws, size_t ws_size,
                              hipStream_t stream) {
    const float* x   = (const float*)d_in[0];
    const float* Wfl = (const float*)d_in[1]; // [7,512,2048] == [3584,2048]
    const float* Wm  = (const float*)d_in[2]; // [2048,3584]
    const float* Wfe = (const float*)d_in[3]; // [2048,3584]
    float* out = (float*)d_out;
    (void)in_sizes; (void)n_in; (void)out_size; (void)ws_size;

    char* ws = (char*)d_ws;
    bf16*  xe_hi  = (bf16*)(ws);                    // 4096x3584 bf16 = 29,360,128
    bf16*  xe_lo  = (bf16*)(ws + 29360128);         // 29,360,128
    float* male   = (float*)(ws + 58720256);        // 4096x2048 f32 = 33,554,432
    float* female = (float*)(ws + 92274688);        // 33,554,432
    // phase-1 region (dead after flower GEMM):
    bf16*  xo_hi  = (bf16*)(ws + 125829120);        // 16,777,216
    bf16*  xo_lo  = (bf16*)(ws + 142606336);        // 16,777,216
    bf16*  Wfl_hi = (bf16*)(ws + 159383552);        // 14,680,064
    bf16*  Wfl_lo = (bf16*)(ws + 174063616);        // end 188,743,680
    // phase-2 overlay of the same region:
    bf16*  Wm_hi  = (bf16*)(ws + 125829120);
    bf16*  Wm_lo  = (bf16*)(ws + 140509184);
    bf16*  Wff_hi = (bf16*)(ws + 155189248);
    bf16*  Wff_lo = (bf16*)(ws + 169869312);        // end 184,549,376

    // 1. vesica scaling (fp32 -> bf16 hi/lo)
    vesica_kernel<<<B_DIM, 256, 0, stream>>>(x, xo_hi, xo_lo);

    // 2. split W_flower
    split_kernel<<<(D_HID * D_IN / 8) / 256, 256, 0, stream>>>(Wfl, Wfl_hi, Wfl_lo);

    // 3. flower GEMM (bf16x3) + phase epilogue -> xe hi/lo [4096,3584]
    gemm3_bt<1><<<dim3(D_HID / 128, B_DIM / 128), 256, 0, stream>>>(
        xo_hi, xo_lo, Wfl_hi, Wfl_lo, (void*)xe_hi, (void*)xe_lo, B_DIM, D_HID, D_IN);

    // 4. split W_male; flip+split W_female (overlays dead phase-1 region)
    split_kernel<<<(D_OUT * D_HID / 8) / 256, 256, 0, stream>>>(Wm, Wm_hi, Wm_lo);
    flipsplit_kernel<<<(D_OUT * (D_HID / 8)) / 256, 256, 0, stream>>>(Wfe, Wff_hi, Wff_lo);

    // 5. male / female GEMMs (bf16x3, fp32 out)
    gemm3_bt<2><<<dim3(D_OUT / 128, B_DIM / 128), 256, 0, stream>>>(
        xe_hi, xe_lo, Wm_hi, Wm_lo, (void*)male, nullptr, B_DIM, D_OUT, D_HID);
    gemm3_bt<2><<<dim3(D_OUT / 128, B_DIM / 128), 256, 0, stream>>>(
        xe_hi, xe_lo, Wff_hi, Wff_lo, (void*)female, nullptr, B_DIM, D_OUT, D_HID);

    // 6. sigmoid phase-lock blend (fp32 out)
    combine_kernel<<<B_DIM, 256, 0, stream>>>(male, female, out);
}

// Round 5
// 628.650 us; speedup vs baseline: 1.1905x; 1.1905x over previous
//
#include <hip/hip_runtime.h>
#include <hip/hip_bf16.h>
#include <math.h>

#define B_DIM 4096
#define D_IN  2048
#define D_HID 3584
#define D_OUT 2048

typedef __bf16 bf16;
typedef float  floatx4 __attribute__((ext_vector_type(4)));
typedef bf16   bf16x8  __attribute__((ext_vector_type(8)));

typedef __attribute__((address_space(1))) const void* gptr1;
typedef __attribute__((address_space(3))) void*       lptr3;

__device__ __forceinline__ void load_lds16(const void* g, void* l) {
    __builtin_amdgcn_global_load_lds((gptr1)g, (lptr3)l, 16, 0, 0);
}

struct HL { bf16 h, l; };
__device__ __forceinline__ HL split2(float v) {
    HL r;
    r.h = (bf16)v;
    r.l = (bf16)(v - (float)r.h);
    return r;
}

// LDS tile: 128 rows x 32 cols bf16, stored as 16B chunks (4/row), chunk c of
// row r lives at chunk slot r*4 + (c ^ (r&3))  -- XOR swizzle kills the
// chunk-column aliasing of the straight layout (R4: 4.4e7 conflict cycles).
__device__ __forceinline__ int frag_off(int rr, int cc) {
    return ((rr << 2) + (cc ^ (rr & 3))) << 3; // element offset of 16B chunk
}

// ---------------------------------------------------------------------------
// Vesica (fp32 in): x_overlap = x * (1 + relu(1 - |dist - 1|)); emit bf16 hi/lo
// ---------------------------------------------------------------------------
__global__ __launch_bounds__(256) void vesica_kernel(const float* __restrict__ x,
                                                     bf16* __restrict__ xh,
                                                     bf16* __restrict__ xl) {
    const int b  = blockIdx.x;
    const int bp = (b == 0) ? (B_DIM - 1) : (b - 1);
    const int t  = threadIdx.x;

    const floatx4* xr = (const floatx4*)(x + (size_t)b  * D_IN);
    const floatx4* pr = (const floatx4*)(x + (size_t)bp * D_IN);
    const floatx4 v0 = xr[t * 2], v1 = xr[t * 2 + 1];
    const floatx4 p0 = pr[t * 2], p1 = pr[t * 2 + 1];

    float s = 0.f;
#pragma unroll
    for (int j = 0; j < 4; ++j) {
        const float d0 = v0[j] - p0[j], d1 = v1[j] - p1[j];
        s += d0 * d0 + d1 * d1;
    }
#pragma unroll
    for (int off = 32; off > 0; off >>= 1) s += __shfl_down(s, off, 64);

    __shared__ float red[4];
    const int wave = t >> 6, lane = t & 63;
    if (lane == 0) red[wave] = s;
    __syncthreads();
    const float dist = sqrtf(red[0] + red[1] + red[2] + red[3]);
    const float sc   = 1.f + fmaxf(0.f, 1.f - fabsf(dist - 1.f));

    bf16x8 h, l;
#pragma unroll
    for (int j = 0; j < 4; ++j) {
        const HL a  = split2(v0[j] * sc);
        const HL b2 = split2(v1[j] * sc);
        h[j] = a.h;      l[j] = a.l;
        h[4 + j] = b2.h; l[4 + j] = b2.l;
    }
    ((bf16x8*)(xh + (size_t)b * D_IN))[t] = h;
    ((bf16x8*)(xl + (size_t)b * D_IN))[t] = l;
}

// ---------------------------------------------------------------------------
// Split fp32 weight array into bf16 hi/lo.
// ---------------------------------------------------------------------------
__global__ __launch_bounds__(256) void split_kernel(const float* __restrict__ w,
                                                    bf16* __restrict__ wh,
                                                    bf16* __restrict__ wl) {
    const size_t i = (size_t)blockIdx.x * 256 + threadIdx.x;
    const floatx4 a = ((const floatx4*)w)[i * 2];
    const floatx4 b = ((const floatx4*)w)[i * 2 + 1];
    bf16x8 h, l;
#pragma unroll
    for (int j = 0; j < 4; ++j) {
        const HL u = split2(a[j]);
        const HL v = split2(b[j]);
        h[j] = u.h;     l[j] = u.l;
        h[4 + j] = v.h; l[4 + j] = v.l;
    }
    ((bf16x8*)wh)[i] = h;
    ((bf16x8*)wl)[i] = l;
}

// ---------------------------------------------------------------------------
// Flip W_female [2048,3584] along axis 1, split into bf16 hi/lo.
// ---------------------------------------------------------------------------
__global__ __launch_bounds__(256) void flipsplit_kernel(const float* __restrict__ w,
                                                        bf16* __restrict__ wh,
                                                        bf16* __restrict__ wl) {
    const int i = blockIdx.x * 256 + threadIdx.x;
    const int o = i / 448;
    const int g = i - o * 448;
    const float* src = w + (size_t)o * 3584 + (size_t)(447 - g) * 8;
    const floatx4 a = ((const floatx4*)src)[0];
    const floatx4 b = ((const floatx4*)src)[1];
    bf16x8 h, l;
#pragma unroll
    for (int j = 0; j < 4; ++j) {
        const HL u = split2(b[3 - j]);   // out[0..3] = src[7..4]
        const HL v = split2(a[3 - j]);   // out[4..7] = src[3..0]
        h[j] = u.h;     l[j] = u.l;
        h[4 + j] = v.h; l[4 + j] = v.l;
    }
    ((bf16x8*)wh)[(size_t)o * 448 + g] = h;
    ((bf16x8*)wl)[(size_t)o * 448 + g] = l;
}

// ---------------------------------------------------------------------------
// Flower GEMM (bf16x3): xe = phase(xo @ Wfl^T), bf16 hi/lo out.
// 128x128 tile, BK=32, 16x16x32 frags, swizzled LDS.
// ---------------------------------------------------------------------------
__global__ __launch_bounds__(256, 4) void gemm3_flower(const bf16* __restrict__ Ah,
                                                       const bf16* __restrict__ Al,
                                                       const bf16* __restrict__ Bh,
                                                       const bf16* __restrict__ Bl,
                                                       bf16* __restrict__ C0,
                                                       bf16* __restrict__ C1,
                                                       int M, int N, int K) {
    __shared__ bf16 sAh[4096], sAl[4096], sBh[4096], sBl[4096];

    const int tid  = threadIdx.x;
    const int wave = tid >> 6;
    const int lane = tid & 63;
    const int m0   = blockIdx.y * 128;
    const int n0   = blockIdx.x * 128;
    const int wm   = wave & 1;
    const int wn   = wave >> 1;

    floatx4 acc[4][4];
#pragma unroll
    for (int i = 0; i < 4; ++i)
#pragma unroll
        for (int j = 0; j < 4; ++j) acc[i][j] = (floatx4){0.f, 0.f, 0.f, 0.f};

    const int lr = lane & 15;   // row within fragment
    const int cc = lane >> 4;   // logical 16B chunk (k/8)

    for (int kt = 0; kt < K; kt += 32) {
#pragma unroll
        for (int i = 0; i < 2; ++i) {
            const int q    = ((i * 4 + wave) << 6) + lane; // LDS chunk slot
            const int r    = q >> 2;
            const int clog = (q & 3) ^ (r & 3);
            const int e    = q << 3;
            const size_t ga = (size_t)(m0 + r) * K + kt + clog * 8;
            const size_t gb = (size_t)(n0 + r) * K + kt + clog * 8;
            load_lds16(&Ah[ga], &sAh[e]);
            load_lds16(&Al[ga], &sAl[e]);
            load_lds16(&Bh[gb], &sBh[e]);
            load_lds16(&Bl[gb], &sBl[e]);
        }
        __syncthreads();

        bf16x8 ah[4], al[4], bh[4], bl[4];
#pragma unroll
        for (int mi = 0; mi < 4; ++mi) {
            const int off = frag_off(wm * 64 + mi * 16 + lr, cc);
            ah[mi] = *(const bf16x8*)&sAh[off];
            al[mi] = *(const bf16x8*)&sAl[off];
        }
#pragma unroll
        for (int ni = 0; ni < 4; ++ni) {
            const int off = frag_off(wn * 64 + ni * 16 + lr, cc);
            bh[ni] = *(const bf16x8*)&sBh[off];
            bl[ni] = *(const bf16x8*)&sBl[off];
        }

#pragma unroll
        for (int mi = 0; mi < 4; ++mi)
#pragma unroll
            for (int ni = 0; ni < 4; ++ni) {
                acc[mi][ni] = __builtin_amdgcn_mfma_f32_16x16x32_bf16(
                    ah[mi], bh[ni], acc[mi][ni], 0, 0, 0);
                acc[mi][ni] = __builtin_amdgcn_mfma_f32_16x16x32_bf16(
                    al[mi], bh[ni], acc[mi][ni], 0, 0, 0);
                acc[mi][ni] = __builtin_amdgcn_mfma_f32_16x16x32_bf16(
                    ah[mi], bl[ni], acc[mi][ni], 0, 0, 0);
            }
        __syncthreads();
    }

    // epilogue: C/D layout col = lane&15, row = (lane>>4)*4 + r  [verified R3]
    const int rq = (lane >> 4) << 2;
    const int cl = lane & 15;
#pragma unroll
    for (int mi = 0; mi < 4; ++mi) {
#pragma unroll
        for (int ni = 0; ni < 4; ++ni) {
            const int col = n0 + wn * 64 + ni * 16 + cl;
            float pm = 1.0f;
            const int jm = col & 511;
            if (jm < 2) {
                const float ph = 0.8975979010256552f * (float)(col >> 9); // 2pi/7*c
                pm = (jm == 0) ? cosf(ph) : sinf(ph);
            }
#pragma unroll
            for (int r = 0; r < 4; ++r) {
                const int row = m0 + wm * 64 + mi * 16 + rq + r;
                const size_t idx = (size_t)row * N + col;
                const HL u = split2(acc[mi][ni][r] * pm);
                C0[idx] = u.h;
                C1[idx] = u.l;
            }
        }
    }
}

// ---------------------------------------------------------------------------
// Dual GEMM (bf16x3): male = xe @ Wm^T, female = xe @ Wff^T in ONE kernel —
// A-tiles staged once for both products. 6 LDS tiles (48 KB), fp32 out.
// ---------------------------------------------------------------------------
__global__ __launch_bounds__(256, 2) void gemm3_dual(const bf16* __restrict__ Ah,
                                                     const bf16* __restrict__ Al,
                                                     const bf16* __restrict__ Bmh,
                                                     const bf16* __restrict__ Bml,
                                                     const bf16* __restrict__ Bfh,
                                                     const bf16* __restrict__ Bfl,
                                                     float* __restrict__ Cm,
                                                     float* __restrict__ Cf,
                                                     int M, int N, int K) {
    __shared__ bf16 sAh[4096], sAl[4096];
    __shared__ bf16 sMh[4096], sMl[4096];
    __shared__ bf16 sFh[4096], sFl[4096];

    const int tid  = threadIdx.x;
    const int wave = tid >> 6;
    const int lane = tid & 63;
    const int m0   = blockIdx.y * 128;
    const int n0   = blockIdx.x * 128;
    const int wm   = wave & 1;
    const int wn   = wave >> 1;

    floatx4 am[4][4], af[4][4];
#pragma unroll
    for (int i = 0; i < 4; ++i)
#pragma unroll
        for (int j = 0; j < 4; ++j) {
            am[i][j] = (floatx4){0.f, 0.f, 0.f, 0.f};
            af[i][j] = (floatx4){0.f, 0.f, 0.f, 0.f};
        }

    const int lr = lane & 15;
    const int cc = lane >> 4;

    for (int kt = 0; kt < K; kt += 32) {
#pragma unroll
        for (int i = 0; i < 2; ++i) {
            const int q    = ((i * 4 + wave) << 6) + lane;
            const int r    = q >> 2;
            const int clog = (q & 3) ^ (r & 3);
            const int e    = q << 3;
            const size_t ga = (size_t)(m0 + r) * K + kt + clog * 8;
            const size_t gb = (size_t)(n0 + r) * K + kt + clog * 8;
            load_lds16(&Ah[ga],  &sAh[e]);
            load_lds16(&Al[ga],  &sAl[e]);
            load_lds16(&Bmh[gb], &sMh[e]);
            load_lds16(&Bml[gb], &sMl[e]);
            load_lds16(&Bfh[gb], &sFh[e]);
            load_lds16(&Bfl[gb], &sFl[e]);
        }
        __syncthreads();

        bf16x8 ah[4], al[4];
#pragma unroll
        for (int mi = 0; mi < 4; ++mi) {
            const int off = frag_off(wm * 64 + mi * 16 + lr, cc);
            ah[mi] = *(const bf16x8*)&sAh[off];
            al[mi] = *(const bf16x8*)&sAl[off];
        }
#pragma unroll
        for (int ni = 0; ni < 4; ++ni) {
            const int off = frag_off(wn * 64 + ni * 16 + lr, cc);
            const bf16x8 mh = *(const bf16x8*)&sMh[off];
            const bf16x8 ml = *(const bf16x8*)&sMl[off];
            const bf16x8 fh = *(const bf16x8*)&sFh[off];
            const bf16x8 fl = *(const bf16x8*)&sFl[off];
#pragma unroll
            for (int mi = 0; mi < 4; ++mi) {
                am[mi][ni] = __builtin_amdgcn_mfma_f32_16x16x32_bf16(
                    ah[mi], mh, am[mi][ni], 0, 0, 0);
                am[mi][ni] = __builtin_amdgcn_mfma_f32_16x16x32_bf16(
                    al[mi], mh, am[mi][ni], 0, 0, 0);
                am[mi][ni] = __builtin_amdgcn_mfma_f32_16x16x32_bf16(
                    ah[mi], ml, am[mi][ni], 0, 0, 0);
                af[mi][ni] = __builtin_amdgcn_mfma_f32_16x16x32_bf16(
                    ah[mi], fh, af[mi][ni], 0, 0, 0);
                af[mi][ni] = __builtin_amdgcn_mfma_f32_16x16x32_bf16(
                    al[mi], fh, af[mi][ni], 0, 0, 0);
                af[mi][ni] = __builtin_amdgcn_mfma_f32_16x16x32_bf16(
                    ah[mi], fl, af[mi][ni], 0, 0, 0);
            }
        }
        __syncthreads();
    }

    const int rq = (lane >> 4) << 2;
    const int cl = lane & 15;
#pragma unroll
    for (int mi = 0; mi < 4; ++mi) {
#pragma unroll
        for (int ni = 0; ni < 4; ++ni) {
            const int col = n0 + wn * 64 + ni * 16 + cl;
#pragma unroll
            for (int r = 0; r < 4; ++r) {
                const int row = m0 + wm * 64 + mi * 16 + rq + r;
                const size_t idx = (size_t)row * N + col;
                Cm[idx] = am[mi][ni][r];
                Cf[idx] = af[mi][ni][r];
            }
        }
    }
}

// ---------------------------------------------------------------------------
// Combine: phase_lock = sigmoid(male . female); out = pl*male + (1-pl)*female
// ---------------------------------------------------------------------------
__global__ __launch_bounds__(256) void combine_kernel(const float* __restrict__ male,
                                                      const float* __restrict__ female,
                                                      float* __restrict__ out) {
    const int b = blockIdx.x;
    const int t = threadIdx.x;

    const floatx4* m4 = (const floatx4*)(male   + (size_t)b * D_OUT);
    const floatx4* f4 = (const floatx4*)(female + (size_t)b * D_OUT);
    const floatx4 mv0 = m4[t * 2], mv1 = m4[t * 2 + 1];
    const floatx4 fv0 = f4[t * 2], fv1 = f4[t * 2 + 1];

    float s = 0.f;
#pragma unroll
    for (int j = 0; j < 4; ++j) s += mv0[j] * fv0[j] + mv1[j] * fv1[j];
#pragma unroll
    for (int off = 32; off > 0; off >>= 1) s += __shfl_down(s, off, 64);

    __shared__ float red[4];
    const int wave = t >> 6, lane = t & 63;
    if (lane == 0) red[wave] = s;
    __syncthreads();
    const float dot = red[0] + red[1] + red[2] + red[3];
    const float pl  = 1.f / (1.f + expf(-dot));

    floatx4 o0, o1;
#pragma unroll
    for (int j = 0; j < 4; ++j) {
        o0[j] = pl * mv0[j] + (1.f - pl) * fv0[j];
        o1[j] = pl * mv1[j] + (1.f - pl) * fv1[j];
    }
    floatx4* o4 = (floatx4*)(out + (size_t)b * D_OUT);
    o4[t * 2]     = o0;
    o4[t * 2 + 1] = o1;
}

// ---------------------------------------------------------------------------
extern "C" void kernel_launch(void* const* d_in, const int* in_sizes, int n_in,
                              void* d_out, int out_size, void* d_ws, size_t ws_size,
                              hipStream_t stream) {
    const float* x   = (const float*)d_in[0];
    const float* Wfl = (const float*)d_in[1]; // [7,512,2048] == [3584,2048]
    const float* Wm  = (const float*)d_in[2]; // [2048,3584]
    const float* Wfe = (const float*)d_in[3]; // [2048,3584]
    float* out = (float*)d_out;
    (void)in_sizes; (void)n_in; (void)out_size; (void)ws_size;

    char* ws = (char*)d_ws;
    bf16*  xe_hi  = (bf16*)(ws);                    // 4096x3584 bf16 = 29,360,128
    bf16*  xe_lo  = (bf16*)(ws + 29360128);         // 29,360,128
    float* male   = (float*)(ws + 58720256);        // 4096x2048 f32 = 33,554,432
    float* female = (float*)(ws + 92274688);        // 33,554,432
    // phase-1 region (dead after flower GEMM):
    bf16*  xo_hi  = (bf16*)(ws + 125829120);        // 16,777,216
    bf16*  xo_lo  = (bf16*)(ws + 142606336);        // 16,777,216
    bf16*  Wfl_hi = (bf16*)(ws + 159383552);        // 14,680,064
    bf16*  Wfl_lo = (bf16*)(ws + 174063616);        // end 188,743,680
    // phase-2 overlay of the same region:
    bf16*  Wm_hi  = (bf16*)(ws + 125829120);
    bf16*  Wm_lo  = (bf16*)(ws + 140509184);
    bf16*  Wff_hi = (bf16*)(ws + 155189248);
    bf16*  Wff_lo = (bf16*)(ws + 169869312);        // end 184,549,376

    // 1. vesica scaling (fp32 -> bf16 hi/lo)
    vesica_kernel<<<B_DIM, 256, 0, stream>>>(x, xo_hi, xo_lo);

    // 2. split W_flower
    split_kernel<<<(D_HID * D_IN / 8) / 256, 256, 0, stream>>>(Wfl, Wfl_hi, Wfl_lo);

    // 3. flower GEMM (bf16x3) + phase epilogue -> xe hi/lo [4096,3584]
    gemm3_flower<<<dim3(D_HID / 128, B_DIM / 128), 256, 0, stream>>>(
        xo_hi, xo_lo, Wfl_hi, Wfl_lo, xe_hi, xe_lo, B_DIM, D_HID, D_IN);

    // 4. split W_male; flip+split W_female (overlays dead phase-1 region)
    split_kernel<<<(D_OUT * D_HID / 8) / 256, 256, 0, stream>>>(Wm, Wm_hi, Wm_lo);
    flipsplit_kernel<<<(D_OUT * (D_HID / 8)) / 256, 256, 0, stream>>>(Wfe, Wff_hi, Wff_lo);

    // 5. fused male+female dual GEMM (bf16x3, fp32 out) — A staged once
    gemm3_dual<<<dim3(D_OUT / 128, B_DIM / 128), 256, 0, stream>>>(
        xe_hi, xe_lo, Wm_hi, Wm_lo, Wff_hi, Wff_lo, male, female,
        B_DIM, D_OUT, D_HID);

    // 6. sigmoid phase-lock blend (fp32 out)
    combine_kernel<<<B_DIM, 256, 0, stream>>>(male, female, out);
}

// Round 6
// 621.952 us; speedup vs baseline: 1.2033x; 1.0108x over previous
//
#include <hip/hip_runtime.h>
#include <hip/hip_bf16.h>
#include <math.h>

#define B_DIM 4096
#define D_IN  2048
#define D_HID 3584
#define D_OUT 2048

typedef __bf16 bf16;
typedef float  floatx4 __attribute__((ext_vector_type(4)));
typedef bf16   bf16x8  __attribute__((ext_vector_type(8)));

typedef __attribute__((address_space(1))) const void* gptr1;
typedef __attribute__((address_space(3))) void*       lptr3;

__device__ __forceinline__ void load_lds16(const void* g, void* l) {
    __builtin_amdgcn_global_load_lds((gptr1)g, (lptr3)l, 16, 0, 0);
}

struct HL { bf16 h, l; };
__device__ __forceinline__ HL split2(float v) {
    HL r;
    r.h = (bf16)v;
    r.l = (bf16)(v - (float)r.h);
    return r;
}

// ---------------------------------------------------------------------------
// Vesica (fp32 in): x_overlap = x * (1 + relu(1 - |dist - 1|)); emit bf16 hi/lo
// ---------------------------------------------------------------------------
__global__ __launch_bounds__(256) void vesica_kernel(const float* __restrict__ x,
                                                     bf16* __restrict__ xh,
                                                     bf16* __restrict__ xl) {
    const int b  = blockIdx.x;
    const int bp = (b == 0) ? (B_DIM - 1) : (b - 1);
    const int t  = threadIdx.x;

    const floatx4* xr = (const floatx4*)(x + (size_t)b  * D_IN);
    const floatx4* pr = (const floatx4*)(x + (size_t)bp * D_IN);
    const floatx4 v0 = xr[t * 2], v1 = xr[t * 2 + 1];
    const floatx4 p0 = pr[t * 2], p1 = pr[t * 2 + 1];

    float s = 0.f;
#pragma unroll
    for (int j = 0; j < 4; ++j) {
        const float d0 = v0[j] - p0[j], d1 = v1[j] - p1[j];
        s += d0 * d0 + d1 * d1;
    }
#pragma unroll
    for (int off = 32; off > 0; off >>= 1) s += __shfl_down(s, off, 64);

    __shared__ float red[4];
    const int wave = t >> 6, lane = t & 63;
    if (lane == 0) red[wave] = s;
    __syncthreads();
    const float dist = sqrtf(red[0] + red[1] + red[2] + red[3]);
    const float sc   = 1.f + fmaxf(0.f, 1.f - fabsf(dist - 1.f));

    bf16x8 h, l;
#pragma unroll
    for (int j = 0; j < 4; ++j) {
        const HL a  = split2(v0[j] * sc);
        const HL b2 = split2(v1[j] * sc);
        h[j] = a.h;      l[j] = a.l;
        h[4 + j] = b2.h; l[4 + j] = b2.l;
    }
    ((bf16x8*)(xh + (size_t)b * D_IN))[t] = h;
    ((bf16x8*)(xl + (size_t)b * D_IN))[t] = l;
}

// ---------------------------------------------------------------------------
// Split fp32 weight array into bf16 hi/lo.
// ---------------------------------------------------------------------------
__global__ __launch_bounds__(256) void split_kernel(const float* __restrict__ w,
                                                    bf16* __restrict__ wh,
                                                    bf16* __restrict__ wl) {
    const size_t i = (size_t)blockIdx.x * 256 + threadIdx.x;
    const floatx4 a = ((const floatx4*)w)[i * 2];
    const floatx4 b = ((const floatx4*)w)[i * 2 + 1];
    bf16x8 h, l;
#pragma unroll
    for (int j = 0; j < 4; ++j) {
        const HL u = split2(a[j]);
        const HL v = split2(b[j]);
        h[j] = u.h;     l[j] = u.l;
        h[4 + j] = v.h; l[4 + j] = v.l;
    }
    ((bf16x8*)wh)[i] = h;
    ((bf16x8*)wl)[i] = l;
}

// ---------------------------------------------------------------------------
// Flip W_female [2048,3584] along axis 1, split into bf16 hi/lo.
// ---------------------------------------------------------------------------
__global__ __launch_bounds__(256) void flipsplit_kernel(const float* __restrict__ w,
                                                        bf16* __restrict__ wh,
                                                        bf16* __restrict__ wl) {
    const int i = blockIdx.x * 256 + threadIdx.x;
    const int o = i / 448;
    const int g = i - o * 448;
    const float* src = w + (size_t)o * 3584 + (size_t)(447 - g) * 8;
    const floatx4 a = ((const floatx4*)src)[0];
    const floatx4 b = ((const floatx4*)src)[1];
    bf16x8 h, l;
#pragma unroll
    for (int j = 0; j < 4; ++j) {
        const HL u = split2(b[3 - j]);   // out[0..3] = src[7..4]
        const HL v = split2(a[3 - j]);   // out[4..7] = src[3..0]
        h[j] = u.h;     l[j] = u.l;
        h[4 + j] = v.h; l[4 + j] = v.l;
    }
    ((bf16x8*)wh)[(size_t)o * 448 + g] = h;
    ((bf16x8*)wl)[(size_t)o * 448 + g] = l;
}

// ---------------------------------------------------------------------------
// Flower GEMM (bf16x3): xe = phase(xo @ Wfl^T), bf16 hi/lo out.
// 128x256 tile, BK=32: B-tile (256 rows) staged once for 2x the output —
// 96 MFMA per wave-iter per 48KB staged, same economics as gemm3_dual.
// Straight LDS layout (R5 swizzle reverted: no conflict gain, coalescing risk)
// ---------------------------------------------------------------------------
__global__ __launch_bounds__(256, 2) void gemm3_flower(const bf16* __restrict__ Ah,
                                                       const bf16* __restrict__ Al,
                                                       const bf16* __restrict__ Bh,
                                                       const bf16* __restrict__ Bl,
                                                       bf16* __restrict__ C0,
                                                       bf16* __restrict__ C1,
                                                       int M, int N, int K) {
    __shared__ bf16 sAh[128 * 32], sAl[128 * 32];
    __shared__ bf16 sBh[256 * 32], sBl[256 * 32];

    const int tid  = threadIdx.x;
    const int wave = tid >> 6;
    const int lane = tid & 63;
    const int m0   = blockIdx.y * 128;
    const int n0   = blockIdx.x * 256;
    const int wm   = wave & 1;   // 64-row half
    const int wn   = wave >> 1;  // 128-col half

    floatx4 acc[4][8];
#pragma unroll
    for (int i = 0; i < 4; ++i)
#pragma unroll
        for (int j = 0; j < 8; ++j) acc[i][j] = (floatx4){0.f, 0.f, 0.f, 0.f};

    const int lr  = lane & 15;
    const int cc8 = (lane >> 4) << 3;

    for (int kt = 0; kt < K; kt += 32) {
        // A tiles: 512 chunks each, 2 per thread
#pragma unroll
        for (int i = 0; i < 2; ++i) {
            const int q = ((i * 4 + wave) << 6) + lane;
            const int r = q >> 2, c = q & 3, e = q << 3;
            const size_t ga = (size_t)(m0 + r) * K + kt + c * 8;
            load_lds16(&Ah[ga], &sAh[e]);
            load_lds16(&Al[ga], &sAl[e]);
        }
        // B tiles: 1024 chunks each, 4 per thread
#pragma unroll
        for (int i = 0; i < 4; ++i) {
            const int q = ((i * 4 + wave) << 6) + lane;
            const int r = q >> 2, c = q & 3, e = q << 3;
            const size_t gb = (size_t)(n0 + r) * K + kt + c * 8;
            load_lds16(&Bh[gb], &sBh[e]);
            load_lds16(&Bl[gb], &sBl[e]);
        }
        __syncthreads();

        bf16x8 ah[4], al[4];
#pragma unroll
        for (int mi = 0; mi < 4; ++mi) {
            const int off = ((wm * 64 + mi * 16 + lr) << 5) + cc8;
            ah[mi] = *(const bf16x8*)&sAh[off];
            al[mi] = *(const bf16x8*)&sAl[off];
        }
#pragma unroll
        for (int ni = 0; ni < 8; ++ni) {
            const int off = ((wn * 128 + ni * 16 + lr) << 5) + cc8;
            const bf16x8 bh = *(const bf16x8*)&sBh[off];
            const bf16x8 bl = *(const bf16x8*)&sBl[off];
#pragma unroll
            for (int mi = 0; mi < 4; ++mi) {
                acc[mi][ni] = __builtin_amdgcn_mfma_f32_16x16x32_bf16(
                    ah[mi], bh, acc[mi][ni], 0, 0, 0);
                acc[mi][ni] = __builtin_amdgcn_mfma_f32_16x16x32_bf16(
                    al[mi], bh, acc[mi][ni], 0, 0, 0);
                acc[mi][ni] = __builtin_amdgcn_mfma_f32_16x16x32_bf16(
                    ah[mi], bl, acc[mi][ni], 0, 0, 0);
            }
        }
        __syncthreads();
    }

    // epilogue: C/D layout col = lane&15, row = (lane>>4)*4 + r  [verified]
    const int rq = (lane >> 4) << 2;
    const int cl = lane & 15;
#pragma unroll
    for (int mi = 0; mi < 4; ++mi) {
#pragma unroll
        for (int ni = 0; ni < 8; ++ni) {
            const int col = n0 + wn * 128 + ni * 16 + cl;
            float pm = 1.0f;
            const int jm = col & 511;
            if (jm < 2) {
                const float ph = 0.8975979010256552f * (float)(col >> 9); // 2pi/7*c
                pm = (jm == 0) ? cosf(ph) : sinf(ph);
            }
#pragma unroll
            for (int r = 0; r < 4; ++r) {
                const int row = m0 + wm * 64 + mi * 16 + rq + r;
                const size_t idx = (size_t)row * N + col;
                const HL u = split2(acc[mi][ni][r] * pm);
                C0[idx] = u.h;
                C1[idx] = u.l;
            }
        }
    }
}

// ---------------------------------------------------------------------------
// Dual GEMM (bf16x3): male = xe @ Wm^T, female = xe @ Wff^T in ONE kernel —
// A-tiles staged once for both products. 6 LDS tiles (48 KB), fp32 out.
// Straight LDS layout.
// ---------------------------------------------------------------------------
__global__ __launch_bounds__(256, 2) void gemm3_dual(const bf16* __restrict__ Ah,
                                                     const bf16* __restrict__ Al,
                                                     const bf16* __restrict__ Bmh,
                                                     const bf16* __restrict__ Bml,
                                                     const bf16* __restrict__ Bfh,
                                                     const bf16* __restrict__ Bfl,
                                                     float* __restrict__ Cm,
                                                     float* __restrict__ Cf,
                                                     int M, int N, int K) {
    __shared__ bf16 sAh[4096], sAl[4096];
    __shared__ bf16 sMh[4096], sMl[4096];
    __shared__ bf16 sFh[4096], sFl[4096];

    const int tid  = threadIdx.x;
    const int wave = tid >> 6;
    const int lane = tid & 63;
    const int m0   = blockIdx.y * 128;
    const int n0   = blockIdx.x * 128;
    const int wm   = wave & 1;
    const int wn   = wave >> 1;

    floatx4 am[4][4], af[4][4];
#pragma unroll
    for (int i = 0; i < 4; ++i)
#pragma unroll
        for (int j = 0; j < 4; ++j) {
            am[i][j] = (floatx4){0.f, 0.f, 0.f, 0.f};
            af[i][j] = (floatx4){0.f, 0.f, 0.f, 0.f};
        }

    const int lr  = lane & 15;
    const int cc8 = (lane >> 4) << 3;

    for (int kt = 0; kt < K; kt += 32) {
#pragma unroll
        for (int i = 0; i < 2; ++i) {
            const int q = ((i * 4 + wave) << 6) + lane;
            const int r = q >> 2, c = q & 3, e = q << 3;
            const size_t ga = (size_t)(m0 + r) * K + kt + c * 8;
            const size_t gb = (size_t)(n0 + r) * K + kt + c * 8;
            load_lds16(&Ah[ga],  &sAh[e]);
            load_lds16(&Al[ga],  &sAl[e]);
            load_lds16(&Bmh[gb], &sMh[e]);
            load_lds16(&Bml[gb], &sMl[e]);
            load_lds16(&Bfh[gb], &sFh[e]);
            load_lds16(&Bfl[gb], &sFl[e]);
        }
        __syncthreads();

        bf16x8 ah[4], al[4];
#pragma unroll
        for (int mi = 0; mi < 4; ++mi) {
            const int off = ((wm * 64 + mi * 16 + lr) << 5) + cc8;
            ah[mi] = *(const bf16x8*)&sAh[off];
            al[mi] = *(const bf16x8*)&sAl[off];
        }
#pragma unroll
        for (int ni = 0; ni < 4; ++ni) {
            const int off = ((wn * 64 + ni * 16 + lr) << 5) + cc8;
            const bf16x8 mh = *(const bf16x8*)&sMh[off];
            const bf16x8 ml = *(const bf16x8*)&sMl[off];
            const bf16x8 fh = *(const bf16x8*)&sFh[off];
            const bf16x8 fl = *(const bf16x8*)&sFl[off];
#pragma unroll
            for (int mi = 0; mi < 4; ++mi) {
                am[mi][ni] = __builtin_amdgcn_mfma_f32_16x16x32_bf16(
                    ah[mi], mh, am[mi][ni], 0, 0, 0);
                am[mi][ni] = __builtin_amdgcn_mfma_f32_16x16x32_bf16(
                    al[mi], mh, am[mi][ni], 0, 0, 0);
                am[mi][ni] = __builtin_amdgcn_mfma_f32_16x16x32_bf16(
                    ah[mi], ml, am[mi][ni], 0, 0, 0);
                af[mi][ni] = __builtin_amdgcn_mfma_f32_16x16x32_bf16(
                    ah[mi], fh, af[mi][ni], 0, 0, 0);
                af[mi][ni] = __builtin_amdgcn_mfma_f32_16x16x32_bf16(
                    al[mi], fh, af[mi][ni], 0, 0, 0);
                af[mi][ni] = __builtin_amdgcn_mfma_f32_16x16x32_bf16(
                    ah[mi], fl, af[mi][ni], 0, 0, 0);
            }
        }
        __syncthreads();
    }

    const int rq = (lane >> 4) << 2;
    const int cl = lane & 15;
#pragma unroll
    for (int mi = 0; mi < 4; ++mi) {
#pragma unroll
        for (int ni = 0; ni < 4; ++ni) {
            const int col = n0 + wn * 64 + ni * 16 + cl;
#pragma unroll
            for (int r = 0; r < 4; ++r) {
                const int row = m0 + wm * 64 + mi * 16 + rq + r;
                const size_t idx = (size_t)row * N + col;
                Cm[idx] = am[mi][ni][r];
                Cf[idx] = af[mi][ni][r];
            }
        }
    }
}

// ---------------------------------------------------------------------------
// Combine: phase_lock = sigmoid(male . female); out = pl*male + (1-pl)*female
// ---------------------------------------------------------------------------
__global__ __launch_bounds__(256) void combine_kernel(const float* __restrict__ male,
                                                      const float* __restrict__ female,
                                                      float* __restrict__ out) {
    const int b = blockIdx.x;
    const int t = threadIdx.x;

    const floatx4* m4 = (const floatx4*)(male   + (size_t)b * D_OUT);
    const floatx4* f4 = (const floatx4*)(female + (size_t)b * D_OUT);
    const floatx4 mv0 = m4[t * 2], mv1 = m4[t * 2 + 1];
    const floatx4 fv0 = f4[t * 2], fv1 = f4[t * 2 + 1];

    float s = 0.f;
#pragma unroll
    for (int j = 0; j < 4; ++j) s += mv0[j] * fv0[j] + mv1[j] * fv1[j];
#pragma unroll
    for (int off = 32; off > 0; off >>= 1) s += __shfl_down(s, off, 64);

    __shared__ float red[4];
    const int wave = t >> 6, lane = t & 63;
    if (lane == 0) red[wave] = s;
    __syncthreads();
    const float dot = red[0] + red[1] + red[2] + red[3];
    const float pl  = 1.f / (1.f + expf(-dot));

    floatx4 o0, o1;
#pragma unroll
    for (int j = 0; j < 4; ++j) {
        o0[j] = pl * mv0[j] + (1.f - pl) * fv0[j];
        o1[j] = pl * mv1[j] + (1.f - pl) * fv1[j];
    }
    floatx4* o4 = (floatx4*)(out + (size_t)b * D_OUT);
    o4[t * 2]     = o0;
    o4[t * 2 + 1] = o1;
}

// ---------------------------------------------------------------------------
extern "C" void kernel_launch(void* const* d_in, const int* in_sizes, int n_in,
                              void* d_out, int out_size, void* d_ws, size_t ws_size,
                              hipStream_t stream) {
    const float* x   = (const float*)d_in[0];
    const float* Wfl = (const float*)d_in[1]; // [7,512,2048] == [3584,2048]
    const float* Wm  = (const float*)d_in[2]; // [2048,3584]
    const float* Wfe = (const float*)d_in[3]; // [2048,3584]
    float* out = (float*)d_out;
    (void)in_sizes; (void)n_in; (void)out_size; (void)ws_size;

    char* ws = (char*)d_ws;
    bf16*  xe_hi  = (bf16*)(ws);                    // 4096x3584 bf16 = 29,360,128
    bf16*  xe_lo  = (bf16*)(ws + 29360128);         // 29,360,128
    float* male   = (float*)(ws + 58720256);        // 4096x2048 f32 = 33,554,432
    float* female = (float*)(ws + 92274688);        // 33,554,432
    // phase-1 region (dead after flower GEMM):
    bf16*  xo_hi  = (bf16*)(ws + 125829120);        // 16,777,216
    bf16*  xo_lo  = (bf16*)(ws + 142606336);        // 16,777,216
    bf16*  Wfl_hi = (bf16*)(ws + 159383552);        // 14,680,064
    bf16*  Wfl_lo = (bf16*)(ws + 174063616);        // end 188,743,680
    // phase-2 overlay of the same region:
    bf16*  Wm_hi  = (bf16*)(ws + 125829120);
    bf16*  Wm_lo  = (bf16*)(ws + 140509184);
    bf16*  Wff_hi = (bf16*)(ws + 155189248);
    bf16*  Wff_lo = (bf16*)(ws + 169869312);        // end 184,549,376

    // 1. vesica scaling (fp32 -> bf16 hi/lo)
    vesica_kernel<<<B_DIM, 256, 0, stream>>>(x, xo_hi, xo_lo);

    // 2. split W_flower
    split_kernel<<<(D_HID * D_IN / 8) / 256, 256, 0, stream>>>(Wfl, Wfl_hi, Wfl_lo);

    // 3. flower GEMM (bf16x3, 128x256 tile) + phase epilogue -> xe hi/lo
    gemm3_flower<<<dim3(D_HID / 256, B_DIM / 128), 256, 0, stream>>>(
        xo_hi, xo_lo, Wfl_hi, Wfl_lo, xe_hi, xe_lo, B_DIM, D_HID, D_IN);

    // 4. split W_male; flip+split W_female (overlays dead phase-1 region)
    split_kernel<<<(D_OUT * D_HID / 8) / 256, 256, 0, stream>>>(Wm, Wm_hi, Wm_lo);
    flipsplit_kernel<<<(D_OUT * (D_HID / 8)) / 256, 256, 0, stream>>>(Wfe, Wff_hi, Wff_lo);

    // 5. fused male+female dual GEMM (bf16x3, fp32 out) — A staged once
    gemm3_dual<<<dim3(D_OUT / 128, B_DIM / 128), 256, 0, stream>>>(
        xe_hi, xe_lo, Wm_hi, Wm_lo, Wff_hi, Wff_lo, male, female,
        B_DIM, D_OUT, D_HID);

    // 6. sigmoid phase-lock blend (fp32 out)
    combine_kernel<<<B_DIM, 256, 0, stream>>>(male, female, out);
}

// Round 8
// 618.499 us; speedup vs baseline: 1.2101x; 1.0056x over previous
//
#include <hip/hip_runtime.h>
#include <hip/hip_bf16.h>
#include <math.h>

#define B_DIM 4096
#define D_IN  2048
#define D_HID 3584
#define D_OUT 2048

typedef __bf16 bf16;
typedef float  floatx4 __attribute__((ext_vector_type(4)));
typedef bf16   bf16x8  __attribute__((ext_vector_type(8)));

typedef __attribute__((address_space(1))) const void* gptr1;
typedef __attribute__((address_space(3))) void*       lptr3;

__device__ __forceinline__ void load_lds16(const void* g, void* l) {
    __builtin_amdgcn_global_load_lds((gptr1)g, (lptr3)l, 16, 0, 0);
}

struct HL { bf16 h, l; };
__device__ __forceinline__ HL split2(float v) {
    HL r;
    r.h = (bf16)v;
    r.l = (bf16)(v - (float)r.h);
    return r;
}

// ---------------------------------------------------------------------------
// Vesica (fp32 in): x_overlap = x * (1 + relu(1 - |dist - 1|)); emit bf16 hi/lo
// ---------------------------------------------------------------------------
__global__ __launch_bounds__(256) void vesica_kernel(const float* __restrict__ x,
                                                     bf16* __restrict__ xh,
                                                     bf16* __restrict__ xl) {
    const int b  = blockIdx.x;
    const int bp = (b == 0) ? (B_DIM - 1) : (b - 1);
    const int t  = threadIdx.x;

    const floatx4* xr = (const floatx4*)(x + (size_t)b  * D_IN);
    const floatx4* pr = (const floatx4*)(x + (size_t)bp * D_IN);
    const floatx4 v0 = xr[t * 2], v1 = xr[t * 2 + 1];
    const floatx4 p0 = pr[t * 2], p1 = pr[t * 2 + 1];

    float s = 0.f;
#pragma unroll
    for (int j = 0; j < 4; ++j) {
        const float d0 = v0[j] - p0[j], d1 = v1[j] - p1[j];
        s += d0 * d0 + d1 * d1;
    }
#pragma unroll
    for (int off = 32; off > 0; off >>= 1) s += __shfl_down(s, off, 64);

    __shared__ float red[4];
    const int wave = t >> 6, lane = t & 63;
    if (lane == 0) red[wave] = s;
    __syncthreads();
    const float dist = sqrtf(red[0] + red[1] + red[2] + red[3]);
    const float sc   = 1.f + fmaxf(0.f, 1.f - fabsf(dist - 1.f));

    bf16x8 h, l;
#pragma unroll
    for (int j = 0; j < 4; ++j) {
        const HL a  = split2(v0[j] * sc);
        const HL b2 = split2(v1[j] * sc);
        h[j] = a.h;      l[j] = a.l;
        h[4 + j] = b2.h; l[4 + j] = b2.l;
    }
    ((bf16x8*)(xh + (size_t)b * D_IN))[t] = h;
    ((bf16x8*)(xl + (size_t)b * D_IN))[t] = l;
}

// ---------------------------------------------------------------------------
// Split fp32 weight array into bf16 hi/lo.
// ---------------------------------------------------------------------------
__global__ __launch_bounds__(256) void split_kernel(const float* __restrict__ w,
                                                    bf16* __restrict__ wh,
                                                    bf16* __restrict__ wl) {
    const size_t i = (size_t)blockIdx.x * 256 + threadIdx.x;
    const floatx4 a = ((const floatx4*)w)[i * 2];
    const floatx4 b = ((const floatx4*)w)[i * 2 + 1];
    bf16x8 h, l;
#pragma unroll
    for (int j = 0; j < 4; ++j) {
        const HL u = split2(a[j]);
        const HL v = split2(b[j]);
        h[j] = u.h;     l[j] = u.l;
        h[4 + j] = v.h; l[4 + j] = v.l;
    }
    ((bf16x8*)wh)[i] = h;
    ((bf16x8*)wl)[i] = l;
}

// ---------------------------------------------------------------------------
// Flip W_female [2048,3584] along axis 1, split into bf16 hi/lo.
// ---------------------------------------------------------------------------
__global__ __launch_bounds__(256) void flipsplit_kernel(const float* __restrict__ w,
                                                        bf16* __restrict__ wh,
                                                        bf16* __restrict__ wl) {
    const int i = blockIdx.x * 256 + threadIdx.x;
    const int o = i / 448;
    const int g = i - o * 448;
    const float* src = w + (size_t)o * 3584 + (size_t)(447 - g) * 8;
    const floatx4 a = ((const floatx4*)src)[0];
    const floatx4 b = ((const floatx4*)src)[1];
    bf16x8 h, l;
#pragma unroll
    for (int j = 0; j < 4; ++j) {
        const HL u = split2(b[3 - j]);   // out[0..3] = src[7..4]
        const HL v = split2(a[3 - j]);   // out[4..7] = src[3..0]
        h[j] = u.h;     l[j] = u.l;
        h[4 + j] = v.h; l[4 + j] = v.l;
    }
    ((bf16x8*)wh)[(size_t)o * 448 + g] = h;
    ((bf16x8*)wl)[(size_t)o * 448 + g] = l;
}

// ---------------------------------------------------------------------------
// Flower GEMM (bf16x3): xe = phase(xo @ Wfl^T), bf16 hi/lo out.
// 128x224 tile, BK=32 -> grid (16, 32) = 512 blocks = exactly 2/CU.
// Chunk counts (R7 bugfix): A = 128 rows x 4 = 512 chunks (2 full passes),
// B = 224 rows x 4 = 896 chunks (3 full passes + 2-wave partial).
// ---------------------------------------------------------------------------
__global__ __launch_bounds__(256, 2) void gemm3_flower(const bf16* __restrict__ Ah,
                                                       const bf16* __restrict__ Al,
                                                       const bf16* __restrict__ Bh,
                                                       const bf16* __restrict__ Bl,
                                                       bf16* __restrict__ C0,
                                                       bf16* __restrict__ C1,
                                                       int M, int N, int K) {
    __shared__ bf16 sAh[128 * 32], sAl[128 * 32];
    __shared__ bf16 sBh[224 * 32], sBl[224 * 32];

    const int tid  = threadIdx.x;
    const int wave = tid >> 6;
    const int lane = tid & 63;
    const int m0   = blockIdx.y * 128;
    const int n0   = blockIdx.x * 224;
    const int wm   = wave & 1;   // 64-row half
    const int wn   = wave >> 1;  // 112-col half

    floatx4 acc[4][7];
#pragma unroll
    for (int i = 0; i < 4; ++i)
#pragma unroll
        for (int j = 0; j < 7; ++j) acc[i][j] = (floatx4){0.f, 0.f, 0.f, 0.f};

    const int lr  = lane & 15;
    const int cc8 = (lane >> 4) << 3;

    for (int kt = 0; kt < K; kt += 32) {
        // A tiles: 512 chunks each -> 2 full 256-thread passes
#pragma unroll
        for (int i = 0; i < 2; ++i) {
            const int q = ((i * 4 + wave) << 6) + lane;
            const int r = q >> 2, c = q & 3, e = q << 3;
            const size_t ga = (size_t)(m0 + r) * K + kt + c * 8;
            load_lds16(&Ah[ga], &sAh[e]);
            load_lds16(&Al[ga], &sAl[e]);
        }
        // B tiles: 896 chunks each -> 3 full passes + 2-wave partial (128)
#pragma unroll
        for (int i = 0; i < 3; ++i) {
            const int q = ((i * 4 + wave) << 6) + lane;
            const int r = q >> 2, c = q & 3, e = q << 3;
            const size_t gb = (size_t)(n0 + r) * K + kt + c * 8;
            load_lds16(&Bh[gb], &sBh[e]);
            load_lds16(&Bl[gb], &sBl[e]);
        }
        if (wave < 2) {
            const int q = 768 + (wave << 6) + lane;
            const int r = q >> 2, c = q & 3, e = q << 3;
            const size_t gb = (size_t)(n0 + r) * K + kt + c * 8;
            load_lds16(&Bh[gb], &sBh[e]);
            load_lds16(&Bl[gb], &sBl[e]);
        }
        __syncthreads();

        bf16x8 ah[4], al[4];
#pragma unroll
        for (int mi = 0; mi < 4; ++mi) {
            const int off = ((wm * 64 + mi * 16 + lr) << 5) + cc8;
            ah[mi] = *(const bf16x8*)&sAh[off];
            al[mi] = *(const bf16x8*)&sAl[off];
        }
#pragma unroll
        for (int ni = 0; ni < 7; ++ni) {
            const int off = ((wn * 112 + ni * 16 + lr) << 5) + cc8;
            const bf16x8 bh = *(const bf16x8*)&sBh[off];
            const bf16x8 bl = *(const bf16x8*)&sBl[off];
#pragma unroll
            for (int mi = 0; mi < 4; ++mi) {
                acc[mi][ni] = __builtin_amdgcn_mfma_f32_16x16x32_bf16(
                    ah[mi], bh, acc[mi][ni], 0, 0, 0);
                acc[mi][ni] = __builtin_amdgcn_mfma_f32_16x16x32_bf16(
                    al[mi], bh, acc[mi][ni], 0, 0, 0);
                acc[mi][ni] = __builtin_amdgcn_mfma_f32_16x16x32_bf16(
                    ah[mi], bl, acc[mi][ni], 0, 0, 0);
            }
        }
        __syncthreads();
    }

    // epilogue: C/D layout col = lane&15, row = (lane>>4)*4 + r  [verified]
    const int rq = (lane >> 4) << 2;
    const int cl = lane & 15;
#pragma unroll
    for (int mi = 0; mi < 4; ++mi) {
#pragma unroll
        for (int ni = 0; ni < 7; ++ni) {
            const int col = n0 + wn * 112 + ni * 16 + cl;
            float pm = 1.0f;
            const int jm = col & 511;
            if (jm < 2) {
                const float ph = 0.8975979010256552f * (float)(col >> 9); // 2pi/7*c
                pm = (jm == 0) ? cosf(ph) : sinf(ph);
            }
#pragma unroll
            for (int r = 0; r < 4; ++r) {
                const int row = m0 + wm * 64 + mi * 16 + rq + r;
                const size_t idx = (size_t)row * N + col;
                const HL u = split2(acc[mi][ni][r] * pm);
                C0[idx] = u.h;
                C1[idx] = u.l;
            }
        }
    }
}

// ---------------------------------------------------------------------------
// Dual GEMM (bf16x3): male = xe @ Wm^T, female = xe @ Wff^T in ONE kernel —
// A-tiles staged once for both products. 6 LDS tiles (48 KB), fp32 out.
// grid (16,32) = 512 blocks = exactly 2/CU. Staging-BW-bound at ~58% MfmaUtil.
// ---------------------------------------------------------------------------
__global__ __launch_bounds__(256, 2) void gemm3_dual(const bf16* __restrict__ Ah,
                                                     const bf16* __restrict__ Al,
                                                     const bf16* __restrict__ Bmh,
                                                     const bf16* __restrict__ Bml,
                                                     const bf16* __restrict__ Bfh,
                                                     const bf16* __restrict__ Bfl,
                                                     float* __restrict__ Cm,
                                                     float* __restrict__ Cf,
                                                     int M, int N, int K) {
    __shared__ bf16 sAh[4096], sAl[4096];
    __shared__ bf16 sMh[4096], sMl[4096];
    __shared__ bf16 sFh[4096], sFl[4096];

    const int tid  = threadIdx.x;
    const int wave = tid >> 6;
    const int lane = tid & 63;
    const int m0   = blockIdx.y * 128;
    const int n0   = blockIdx.x * 128;
    const int wm   = wave & 1;
    const int wn   = wave >> 1;

    floatx4 am[4][4], af[4][4];
#pragma unroll
    for (int i = 0; i < 4; ++i)
#pragma unroll
        for (int j = 0; j < 4; ++j) {
            am[i][j] = (floatx4){0.f, 0.f, 0.f, 0.f};
            af[i][j] = (floatx4){0.f, 0.f, 0.f, 0.f};
        }

    const int lr  = lane & 15;
    const int cc8 = (lane >> 4) << 3;

    for (int kt = 0; kt < K; kt += 32) {
#pragma unroll
        for (int i = 0; i < 2; ++i) {
            const int q = ((i * 4 + wave) << 6) + lane;
            const int r = q >> 2, c = q & 3, e = q << 3;
            const size_t ga = (size_t)(m0 + r) * K + kt + c * 8;
            const size_t gb = (size_t)(n0 + r) * K + kt + c * 8;
            load_lds16(&Ah[ga],  &sAh[e]);
            load_lds16(&Al[ga],  &sAl[e]);
            load_lds16(&Bmh[gb], &sMh[e]);
            load_lds16(&Bml[gb], &sMl[e]);
            load_lds16(&Bfh[gb], &sFh[e]);
            load_lds16(&Bfl[gb], &sFl[e]);
        }
        __syncthreads();

        bf16x8 ah[4], al[4];
#pragma unroll
        for (int mi = 0; mi < 4; ++mi) {
            const int off = ((wm * 64 + mi * 16 + lr) << 5) + cc8;
            ah[mi] = *(const bf16x8*)&sAh[off];
            al[mi] = *(const bf16x8*)&sAl[off];
        }
#pragma unroll
        for (int ni = 0; ni < 4; ++ni) {
            const int off = ((wn * 64 + ni * 16 + lr) << 5) + cc8;
            const bf16x8 mh = *(const bf16x8*)&sMh[off];
            const bf16x8 ml = *(const bf16x8*)&sMl[off];
            const bf16x8 fh = *(const bf16x8*)&sFh[off];
            const bf16x8 fl = *(const bf16x8*)&sFl[off];
#pragma unroll
            for (int mi = 0; mi < 4; ++mi) {
                am[mi][ni] = __builtin_amdgcn_mfma_f32_16x16x32_bf16(
                    ah[mi], mh, am[mi][ni], 0, 0, 0);
                am[mi][ni] = __builtin_amdgcn_mfma_f32_16x16x32_bf16(
                    al[mi], mh, am[mi][ni], 0, 0, 0);
                am[mi][ni] = __builtin_amdgcn_mfma_f32_16x16x32_bf16(
                    ah[mi], ml, am[mi][ni], 0, 0, 0);
                af[mi][ni] = __builtin_amdgcn_mfma_f32_16x16x32_bf16(
                    ah[mi], fh, af[mi][ni], 0, 0, 0);
                af[mi][ni] = __builtin_amdgcn_mfma_f32_16x16x32_bf16(
                    al[mi], fh, af[mi][ni], 0, 0, 0);
                af[mi][ni] = __builtin_amdgcn_mfma_f32_16x16x32_bf16(
                    ah[mi], fl, af[mi][ni], 0, 0, 0);
            }
        }
        __syncthreads();
    }

    const int rq = (lane >> 4) << 2;
    const int cl = lane & 15;
#pragma unroll
    for (int mi = 0; mi < 4; ++mi) {
#pragma unroll
        for (int ni = 0; ni < 4; ++ni) {
            const int col = n0 + wn * 64 + ni * 16 + cl;
#pragma unroll
            for (int r = 0; r < 4; ++r) {
                const int row = m0 + wm * 64 + mi * 16 + rq + r;
                const size_t idx = (size_t)row * N + col;
                Cm[idx] = am[mi][ni][r];
                Cf[idx] = af[mi][ni][r];
            }
        }
    }
}

// ---------------------------------------------------------------------------
// Combine: phase_lock = sigmoid(male . female); out = pl*male + (1-pl)*female
// ---------------------------------------------------------------------------
__global__ __launch_bounds__(256) void combine_kernel(const float* __restrict__ male,
                                                      const float* __restrict__ female,
                                                      float* __restrict__ out) {
    const int b = blockIdx.x;
    const int t = threadIdx.x;

    const floatx4* m4 = (const floatx4*)(male   + (size_t)b * D_OUT);
    const floatx4* f4 = (const floatx4*)(female + (size_t)b * D_OUT);
    const floatx4 mv0 = m4[t * 2], mv1 = m4[t * 2 + 1];
    const floatx4 fv0 = f4[t * 2], fv1 = f4[t * 2 + 1];

    float s = 0.f;
#pragma unroll
    for (int j = 0; j < 4; ++j) s += mv0[j] * fv0[j] + mv1[j] * fv1[j];
#pragma unroll
    for (int off = 32; off > 0; off >>= 1) s += __shfl_down(s, off, 64);

    __shared__ float red[4];
    const int wave = t >> 6, lane = t & 63;
    if (lane == 0) red[wave] = s;
    __syncthreads();
    const float dot = red[0] + red[1] + red[2] + red[3];
    const float pl  = 1.f / (1.f + expf(-dot));

    floatx4 o0, o1;
#pragma unroll
    for (int j = 0; j < 4; ++j) {
        o0[j] = pl * mv0[j] + (1.f - pl) * fv0[j];
        o1[j] = pl * mv1[j] + (1.f - pl) * fv1[j];
    }
    floatx4* o4 = (floatx4*)(out + (size_t)b * D_OUT);
    o4[t * 2]     = o0;
    o4[t * 2 + 1] = o1;
}

// ---------------------------------------------------------------------------
extern "C" void kernel_launch(void* const* d_in, const int* in_sizes, int n_in,
                              void* d_out, int out_size, void* d_ws, size_t ws_size,
                              hipStream_t stream) {
    const float* x   = (const float*)d_in[0];
    const float* Wfl = (const float*)d_in[1]; // [7,512,2048] == [3584,2048]
    const float* Wm  = (const float*)d_in[2]; // [2048,3584]
    const float* Wfe = (const float*)d_in[3]; // [2048,3584]
    float* out = (float*)d_out;
    (void)in_sizes; (void)n_in; (void)out_size; (void)ws_size;

    char* ws = (char*)d_ws;
    bf16*  xe_hi  = (bf16*)(ws);                    // 4096x3584 bf16 = 29,360,128
    bf16*  xe_lo  = (bf16*)(ws + 29360128);         // 29,360,128
    float* male   = (float*)(ws + 58720256);        // 4096x2048 f32 = 33,554,432
    float* female = (float*)(ws + 92274688);        // 33,554,432
    // phase-1 region (dead after flower GEMM):
    bf16*  xo_hi  = (bf16*)(ws + 125829120);        // 16,777,216
    bf16*  xo_lo  = (bf16*)(ws + 142606336);        // 16,777,216
    bf16*  Wfl_hi = (bf16*)(ws + 159383552);        // 14,680,064
    bf16*  Wfl_lo = (bf16*)(ws + 174063616);        // end 188,743,680
    // phase-2 overlay of the same region:
    bf16*  Wm_hi  = (bf16*)(ws + 125829120);
    bf16*  Wm_lo  = (bf16*)(ws + 140509184);
    bf16*  Wff_hi = (bf16*)(ws + 155189248);
    bf16*  Wff_lo = (bf16*)(ws + 169869312);        // end 184,549,376

    // 1. vesica scaling (fp32 -> bf16 hi/lo)
    vesica_kernel<<<B_DIM, 256, 0, stream>>>(x, xo_hi, xo_lo);

    // 2. split W_flower
    split_kernel<<<(D_HID * D_IN / 8) / 256, 256, 0, stream>>>(Wfl, Wfl_hi, Wfl_lo);

    // 3. flower GEMM (bf16x3, 128x224 tile, 512 blocks) + phase epilogue
    gemm3_flower<<<dim3(D_HID / 224, B_DIM / 128), 256, 0, stream>>>(
        xo_hi, xo_lo, Wfl_hi, Wfl_lo, xe_hi, xe_lo, B_DIM, D_HID, D_IN);

    // 4. split W_male; flip+split W_female (overlays dead phase-1 region)
    split_kernel<<<(D_OUT * D_HID / 8) / 256, 256, 0, stream>>>(Wm, Wm_hi, Wm_lo);
    flipsplit_kernel<<<(D_OUT * (D_HID / 8)) / 256, 256, 0, stream>>>(Wfe, Wff_hi, Wff_lo);

    // 5. fused male+female dual GEMM (bf16x3, fp32 out) — A staged once
    gemm3_dual<<<dim3(D_OUT / 128, B_DIM / 128), 256, 0, stream>>>(
        xe_hi, xe_lo, Wm_hi, Wm_lo, Wff_hi, Wff_lo, male, female,
        B_DIM, D_OUT, D_HID);

    // 6. sigmoid phase-lock blend (fp32 out)
    combine_kernel<<<B_DIM, 256, 0, stream>>>(male, female, out);
}

// Round 9
// 526.297 us; speedup vs baseline: 1.4220x; 1.1752x over previous
//
#include <hip/hip_runtime.h>
#include <hip/hip_bf16.h>
#include <math.h>

#define B_DIM 4096
#define D_IN  2048
#define D_HID 3584
#define D_OUT 2048

typedef __bf16 bf16;
typedef float  floatx4 __attribute__((ext_vector_type(4)));
typedef bf16   bf16x8  __attribute__((ext_vector_type(8)));
typedef bf16   bf16x4  __attribute__((ext_vector_type(4)));

typedef __attribute__((address_space(1))) const void* gptr1;
typedef __attribute__((address_space(3))) void*       lptr3;

__device__ __forceinline__ void load_lds16(const void* g, void* l) {
    __builtin_amdgcn_global_load_lds((gptr1)g, (lptr3)l, 16, 0, 0);
}

struct HL { bf16 h, l; };
__device__ __forceinline__ HL split2(float v) {
    HL r;
    r.h = (bf16)v;
    r.l = (bf16)(v - (float)r.h);
    return r;
}

// ---------------------------------------------------------------------------
// Vesica (fp32 in): x_overlap = x * (1 + relu(1 - |dist - 1|)); emit bf16 hi/lo
// ---------------------------------------------------------------------------
__global__ __launch_bounds__(256) void vesica_kernel(const float* __restrict__ x,
                                                     bf16* __restrict__ xh,
                                                     bf16* __restrict__ xl) {
    const int b  = blockIdx.x;
    const int bp = (b == 0) ? (B_DIM - 1) : (b - 1);
    const int t  = threadIdx.x;

    const floatx4* xr = (const floatx4*)(x + (size_t)b  * D_IN);
    const floatx4* pr = (const floatx4*)(x + (size_t)bp * D_IN);
    const floatx4 v0 = xr[t * 2], v1 = xr[t * 2 + 1];
    const floatx4 p0 = pr[t * 2], p1 = pr[t * 2 + 1];

    float s = 0.f;
#pragma unroll
    for (int j = 0; j < 4; ++j) {
        const float d0 = v0[j] - p0[j], d1 = v1[j] - p1[j];
        s += d0 * d0 + d1 * d1;
    }
#pragma unroll
    for (int off = 32; off > 0; off >>= 1) s += __shfl_down(s, off, 64);

    __shared__ float red[4];
    const int wave = t >> 6, lane = t & 63;
    if (lane == 0) red[wave] = s;
    __syncthreads();
    const float dist = sqrtf(red[0] + red[1] + red[2] + red[3]);
    const float sc   = 1.f + fmaxf(0.f, 1.f - fabsf(dist - 1.f));

    bf16x8 h, l;
#pragma unroll
    for (int j = 0; j < 4; ++j) {
        const HL a  = split2(v0[j] * sc);
        const HL b2 = split2(v1[j] * sc);
        h[j] = a.h;      l[j] = a.l;
        h[4 + j] = b2.h; l[4 + j] = b2.l;
    }
    ((bf16x8*)(xh + (size_t)b * D_IN))[t] = h;
    ((bf16x8*)(xl + (size_t)b * D_IN))[t] = l;
}

// ---------------------------------------------------------------------------
// Split fp32 weight array into bf16 hi/lo.
// ---------------------------------------------------------------------------
__global__ __launch_bounds__(256) void split_kernel(const float* __restrict__ w,
                                                    bf16* __restrict__ wh,
                                                    bf16* __restrict__ wl) {
    const size_t i = (size_t)blockIdx.x * 256 + threadIdx.x;
    const floatx4 a = ((const floatx4*)w)[i * 2];
    const floatx4 b = ((const floatx4*)w)[i * 2 + 1];
    bf16x8 h, l;
#pragma unroll
    for (int j = 0; j < 4; ++j) {
        const HL u = split2(a[j]);
        const HL v = split2(b[j]);
        h[j] = u.h;     l[j] = u.l;
        h[4 + j] = v.h; l[4 + j] = v.l;
    }
    ((bf16x8*)wh)[i] = h;
    ((bf16x8*)wl)[i] = l;
}

// ---------------------------------------------------------------------------
// Flip W_female [2048,3584] along axis 1, split into bf16 hi/lo.
// ---------------------------------------------------------------------------
__global__ __launch_bounds__(256) void flipsplit_kernel(const float* __restrict__ w,
                                                        bf16* __restrict__ wh,
                                                        bf16* __restrict__ wl) {
    const int i = blockIdx.x * 256 + threadIdx.x;
    const int o = i / 448;
    const int g = i - o * 448;
    const float* src = w + (size_t)o * 3584 + (size_t)(447 - g) * 8;
    const floatx4 a = ((const floatx4*)src)[0];
    const floatx4 b = ((const floatx4*)src)[1];
    bf16x8 h, l;
#pragma unroll
    for (int j = 0; j < 4; ++j) {
        const HL u = split2(b[3 - j]);   // out[0..3] = src[7..4]
        const HL v = split2(a[3 - j]);   // out[4..7] = src[3..0]
        h[j] = u.h;     l[j] = u.l;
        h[4 + j] = v.h; l[4 + j] = v.l;
    }
    ((bf16x8*)wh)[(size_t)o * 448 + g] = h;
    ((bf16x8*)wl)[(size_t)o * 448 + g] = l;
}

// ---------------------------------------------------------------------------
// Transpose + phase-scale + split: WflT[d,h] = P(h) * Wfl[h,d], bf16 hi/lo.
// P(h) = cos/sin(2pi*(h>>9)/7) for h%512 in {0,1}, else 1. 64x64 LDS tile.
// ---------------------------------------------------------------------------
__global__ __launch_bounds__(256) void tsplit_kernel(const float* __restrict__ w,
                                                     bf16* __restrict__ th,
                                                     bf16* __restrict__ tl) {
    __shared__ float tile[64][65];
    const int d0 = blockIdx.x * 64;   // 32 tiles along d
    const int h0 = blockIdx.y * 64;   // 56 tiles along h
    const int t  = threadIdx.x;
    const int r  = t >> 4;            // 0..15
    const int cg = (t & 15) << 2;     // 0..60

#pragma unroll
    for (int i = 0; i < 4; ++i) {
        const int hr = r + i * 16;
        const floatx4 v = *(const floatx4*)&w[(size_t)(h0 + hr) * 2048 + d0 + cg];
        tile[hr][cg]     = v[0];
        tile[hr][cg + 1] = v[1];
        tile[hr][cg + 2] = v[2];
        tile[hr][cg + 3] = v[3];
    }
    __syncthreads();

    float pm[4];
#pragma unroll
    for (int j = 0; j < 4; ++j) {
        const int h  = h0 + cg + j;
        const int hm = h & 511;
        float p = 1.f;
        if (hm < 2) {
            const float ph = 0.8975979010256552f * (float)(h >> 9); // 2pi/7*c
            p = (hm == 0) ? cosf(ph) : sinf(ph);
        }
        pm[j] = p;
    }

#pragma unroll
    for (int i = 0; i < 4; ++i) {
        const int dr = r + i * 16;
        bf16x4 hh, ll;
#pragma unroll
        for (int j = 0; j < 4; ++j) {
            const HL u = split2(tile[cg + j][dr] * pm[j]);
            hh[j] = u.h;
            ll[j] = u.l;
        }
        const size_t o = (size_t)(d0 + dr) * 3584 + h0 + cg;
        *(bf16x4*)&th[o] = hh;
        *(bf16x4*)&tl[o] = ll;
    }
}

// ---------------------------------------------------------------------------
// Single bf16x3 GEMM, C = A @ B^T, bf16 hi/lo output (R3-proven 128x128 shape).
// Used for the weight combine: Wc[4096,2048] = Wcat[4096,3584] @ WflT^T.
// ---------------------------------------------------------------------------
__global__ __launch_bounds__(256) void gemm3_single(const bf16* __restrict__ Ah,
                                                    const bf16* __restrict__ Al,
                                                    const bf16* __restrict__ Bh,
                                                    const bf16* __restrict__ Bl,
                                                    bf16* __restrict__ C0,
                                                    bf16* __restrict__ C1,
                                                    int M, int N, int K) {
    __shared__ bf16 sAh[4096], sAl[4096], sBh[4096], sBl[4096];

    const int tid  = threadIdx.x;
    const int wave = tid >> 6;
    const int lane = tid & 63;
    const int m0   = blockIdx.y * 128;
    const int n0   = blockIdx.x * 128;
    const int wm   = wave & 1;
    const int wn   = wave >> 1;

    floatx4 acc[4][4];
#pragma unroll
    for (int i = 0; i < 4; ++i)
#pragma unroll
        for (int j = 0; j < 4; ++j) acc[i][j] = (floatx4){0.f, 0.f, 0.f, 0.f};

    const int lr  = lane & 15;
    const int cc8 = (lane >> 4) << 3;

    for (int kt = 0; kt < K; kt += 32) {
#pragma unroll
        for (int i = 0; i < 2; ++i) {
            const int q = ((i * 4 + wave) << 6) + lane;
            const int r = q >> 2, c = q & 3, e = q << 3;
            const size_t ga = (size_t)(m0 + r) * K + kt + c * 8;
            const size_t gb = (size_t)(n0 + r) * K + kt + c * 8;
            load_lds16(&Ah[ga], &sAh[e]);
            load_lds16(&Al[ga], &sAl[e]);
            load_lds16(&Bh[gb], &sBh[e]);
            load_lds16(&Bl[gb], &sBl[e]);
        }
        __syncthreads();

        bf16x8 ah[4], al[4], bh[4], bl[4];
#pragma unroll
        for (int mi = 0; mi < 4; ++mi) {
            const int off = ((wm * 64 + mi * 16 + lr) << 5) + cc8;
            ah[mi] = *(const bf16x8*)&sAh[off];
            al[mi] = *(const bf16x8*)&sAl[off];
        }
#pragma unroll
        for (int ni = 0; ni < 4; ++ni) {
            const int off = ((wn * 64 + ni * 16 + lr) << 5) + cc8;
            bh[ni] = *(const bf16x8*)&sBh[off];
            bl[ni] = *(const bf16x8*)&sBl[off];
        }

#pragma unroll
        for (int mi = 0; mi < 4; ++mi)
#pragma unroll
            for (int ni = 0; ni < 4; ++ni) {
                acc[mi][ni] = __builtin_amdgcn_mfma_f32_16x16x32_bf16(
                    ah[mi], bh[ni], acc[mi][ni], 0, 0, 0);
                acc[mi][ni] = __builtin_amdgcn_mfma_f32_16x16x32_bf16(
                    al[mi], bh[ni], acc[mi][ni], 0, 0, 0);
                acc[mi][ni] = __builtin_amdgcn_mfma_f32_16x16x32_bf16(
                    ah[mi], bl[ni], acc[mi][ni], 0, 0, 0);
            }
        __syncthreads();
    }

    const int rq = (lane >> 4) << 2;
    const int cl = lane & 15;
#pragma unroll
    for (int mi = 0; mi < 4; ++mi) {
#pragma unroll
        for (int ni = 0; ni < 4; ++ni) {
            const int col = n0 + wn * 64 + ni * 16 + cl;
#pragma unroll
            for (int r = 0; r < 4; ++r) {
                const int row = m0 + wm * 64 + mi * 16 + rq + r;
                const size_t idx = (size_t)row * N + col;
                const HL u = split2(acc[mi][ni][r]);
                C0[idx] = u.h;
                C1[idx] = u.l;
            }
        }
    }
}

// ---------------------------------------------------------------------------
// Dual GEMM (bf16x3): male = xo @ Wcm^T, female = xo @ Wcf^T in ONE kernel —
// A-tiles staged once for both products. 6 LDS tiles (48 KB), fp32 out.
// ---------------------------------------------------------------------------
__global__ __launch_bounds__(256, 2) void gemm3_dual(const bf16* __restrict__ Ah,
                                                     const bf16* __restrict__ Al,
                                                     const bf16* __restrict__ Bmh,
                                                     const bf16* __restrict__ Bml,
                                                     const bf16* __restrict__ Bfh,
                                                     const bf16* __restrict__ Bfl,
                                                     float* __restrict__ Cm,
                                                     float* __restrict__ Cf,
                                                     int M, int N, int K) {
    __shared__ bf16 sAh[4096], sAl[4096];
    __shared__ bf16 sMh[4096], sMl[4096];
    __shared__ bf16 sFh[4096], sFl[4096];

    const int tid  = threadIdx.x;
    const int wave = tid >> 6;
    const int lane = tid & 63;
    const int m0   = blockIdx.y * 128;
    const int n0   = blockIdx.x * 128;
    const int wm   = wave & 1;
    const int wn   = wave >> 1;

    floatx4 am[4][4], af[4][4];
#pragma unroll
    for (int i = 0; i < 4; ++i)
#pragma unroll
        for (int j = 0; j < 4; ++j) {
            am[i][j] = (floatx4){0.f, 0.f, 0.f, 0.f};
            af[i][j] = (floatx4){0.f, 0.f, 0.f, 0.f};
        }

    const int lr  = lane & 15;
    const int cc8 = (lane >> 4) << 3;

    for (int kt = 0; kt < K; kt += 32) {
#pragma unroll
        for (int i = 0; i < 2; ++i) {
            const int q = ((i * 4 + wave) << 6) + lane;
            const int r = q >> 2, c = q & 3, e = q << 3;
            const size_t ga = (size_t)(m0 + r) * K + kt + c * 8;
            const size_t gb = (size_t)(n0 + r) * K + kt + c * 8;
            load_lds16(&Ah[ga],  &sAh[e]);
            load_lds16(&Al[ga],  &sAl[e]);
            load_lds16(&Bmh[gb], &sMh[e]);
            load_lds16(&Bml[gb], &sMl[e]);
            load_lds16(&Bfh[gb], &sFh[e]);
            load_lds16(&Bfl[gb], &sFl[e]);
        }
        __syncthreads();

        bf16x8 ah[4], al[4];
#pragma unroll
        for (int mi = 0; mi < 4; ++mi) {
            const int off = ((wm * 64 + mi * 16 + lr) << 5) + cc8;
            ah[mi] = *(const bf16x8*)&sAh[off];
            al[mi] = *(const bf16x8*)&sAl[off];
        }
#pragma unroll
        for (int ni = 0; ni < 4; ++ni) {
            const int off = ((wn * 64 + ni * 16 + lr) << 5) + cc8;
            const bf16x8 mh = *(const bf16x8*)&sMh[off];
            const bf16x8 ml = *(const bf16x8*)&sMl[off];
            const bf16x8 fh = *(const bf16x8*)&sFh[off];
            const bf16x8 fl = *(const bf16x8*)&sFl[off];
#pragma unroll
            for (int mi = 0; mi < 4; ++mi) {
                am[mi][ni] = __builtin_amdgcn_mfma_f32_16x16x32_bf16(
                    ah[mi], mh, am[mi][ni], 0, 0, 0);
                am[mi][ni] = __builtin_amdgcn_mfma_f32_16x16x32_bf16(
                    al[mi], mh, am[mi][ni], 0, 0, 0);
                am[mi][ni] = __builtin_amdgcn_mfma_f32_16x16x32_bf16(
                    ah[mi], ml, am[mi][ni], 0, 0, 0);
                af[mi][ni] = __builtin_amdgcn_mfma_f32_16x16x32_bf16(
                    ah[mi], fh, af[mi][ni], 0, 0, 0);
                af[mi][ni] = __builtin_amdgcn_mfma_f32_16x16x32_bf16(
                    al[mi], fh, af[mi][ni], 0, 0, 0);
                af[mi][ni] = __builtin_amdgcn_mfma_f32_16x16x32_bf16(
                    ah[mi], fl, af[mi][ni], 0, 0, 0);
            }
        }
        __syncthreads();
    }

    const int rq = (lane >> 4) << 2;
    const int cl = lane & 15;
#pragma unroll
    for (int mi = 0; mi < 4; ++mi) {
#pragma unroll
        for (int ni = 0; ni < 4; ++ni) {
            const int col = n0 + wn * 64 + ni * 16 + cl;
#pragma unroll
            for (int r = 0; r < 4; ++r) {
                const int row = m0 + wm * 64 + mi * 16 + rq + r;
                const size_t idx = (size_t)row * N + col;
                Cm[idx] = am[mi][ni][r];
                Cf[idx] = af[mi][ni][r];
            }
        }
    }
}

// ---------------------------------------------------------------------------
// Combine: phase_lock = sigmoid(male . female); out = pl*male + (1-pl)*female
// ---------------------------------------------------------------------------
__global__ __launch_bounds__(256) void combine_kernel(const float* __restrict__ male,
                                                      const float* __restrict__ female,
                                                      float* __restrict__ out) {
    const int b = blockIdx.x;
    const int t = threadIdx.x;

    const floatx4* m4 = (const floatx4*)(male   + (size_t)b * D_OUT);
    const floatx4* f4 = (const floatx4*)(female + (size_t)b * D_OUT);
    const floatx4 mv0 = m4[t * 2], mv1 = m4[t * 2 + 1];
    const floatx4 fv0 = f4[t * 2], fv1 = f4[t * 2 + 1];

    float s = 0.f;
#pragma unroll
    for (int j = 0; j < 4; ++j) s += mv0[j] * fv0[j] + mv1[j] * fv1[j];
#pragma unroll
    for (int off = 32; off > 0; off >>= 1) s += __shfl_down(s, off, 64);

    __shared__ float red[4];
    const int wave = t >> 6, lane = t & 63;
    if (lane == 0) red[wave] = s;
    __syncthreads();
    const float dot = red[0] + red[1] + red[2] + red[3];
    const float pl  = 1.f / (1.f + expf(-dot));

    floatx4 o0, o1;
#pragma unroll
    for (int j = 0; j < 4; ++j) {
        o0[j] = pl * mv0[j] + (1.f - pl) * fv0[j];
        o1[j] = pl * mv1[j] + (1.f - pl) * fv1[j];
    }
    floatx4* o4 = (floatx4*)(out + (size_t)b * D_OUT);
    o4[t * 2]     = o0;
    o4[t * 2 + 1] = o1;
}

// ---------------------------------------------------------------------------
// Pipeline:  male = xo @ (Wm P Wfl)^T,  female = xo @ (Wfe_flip P Wfl)^T
//   1. vesica: xo hi/lo
//   2. tsplit: WflT[d,h] = P(h) Wfl[h,d]  hi/lo
//   3. split/flipsplit: Wcat = [Wm ; Wfe_flip]  hi/lo
//   4. gemm3_single: Wc[4096,2048] = Wcat @ WflT^T (bf16x3, hi/lo out)
//   5. gemm3_dual:  male/female = xo @ Wc^T (K=2048, fp32 out)
//   6. combine
// ---------------------------------------------------------------------------
extern "C" void kernel_launch(void* const* d_in, const int* in_sizes, int n_in,
                              void* d_out, int out_size, void* d_ws, size_t ws_size,
                              hipStream_t stream) {
    const float* x   = (const float*)d_in[0];
    const float* Wfl = (const float*)d_in[1]; // [7,512,2048] == [3584,2048]
    const float* Wm  = (const float*)d_in[2]; // [2048,3584]
    const float* Wfe = (const float*)d_in[3]; // [2048,3584]
    float* out = (float*)d_out;
    (void)in_sizes; (void)n_in; (void)out_size; (void)ws_size;

    char* ws = (char*)d_ws;
    bf16*  xo_hi   = (bf16*)(ws);                    // 4096x2048 = 16,777,216
    bf16*  xo_lo   = (bf16*)(ws + 16777216);         // 16,777,216
    bf16*  Wc_hi   = (bf16*)(ws + 33554432);         // 4096x2048 = 16,777,216
    bf16*  Wc_lo   = (bf16*)(ws + 50331648);         // 16,777,216 -> 67,108,864
    // overlay phase A (dead after gemm3_single):
    bf16*  WflT_hi = (bf16*)(ws + 67108864);         // 2048x3584 = 14,680,064
    bf16*  WflT_lo = (bf16*)(ws + 81788928);         // -> 96,468,992
    bf16*  Wcat_hi = (bf16*)(ws + 96468992);         // 4096x3584 = 29,360,128
    bf16*  Wcat_lo = (bf16*)(ws + 125829120);        // -> 155,189,248
    // overlay phase B (after gemm3_single):
    float* male    = (float*)(ws + 67108864);        // 4096x2048 f32 = 33,554,432
    float* female  = (float*)(ws + 100663296);       // -> 134,217,728

    // 1. vesica scaling (fp32 -> bf16 hi/lo)
    vesica_kernel<<<B_DIM, 256, 0, stream>>>(x, xo_hi, xo_lo);

    // 2. transpose + phase-scale + split Wfl -> WflT [2048, 3584]
    tsplit_kernel<<<dim3(D_IN / 64, D_HID / 64), 256, 0, stream>>>(Wfl, WflT_hi, WflT_lo);

    // 3. Wcat = [Wm ; Wfe_flip], bf16 hi/lo [4096, 3584]
    split_kernel<<<(D_OUT * D_HID / 8) / 256, 256, 0, stream>>>(Wm, Wcat_hi, Wcat_lo);
    flipsplit_kernel<<<(D_OUT * (D_HID / 8)) / 256, 256, 0, stream>>>(
        Wfe, Wcat_hi + (size_t)D_OUT * D_HID, Wcat_lo + (size_t)D_OUT * D_HID);

    // 4. weight combine: Wc[4096,2048] = Wcat @ WflT^T  (K=3584)
    gemm3_single<<<dim3(D_IN / 128, (2 * D_OUT) / 128), 256, 0, stream>>>(
        Wcat_hi, Wcat_lo, WflT_hi, WflT_lo, Wc_hi, Wc_lo,
        2 * D_OUT, D_IN, D_HID);

    // 5. main dual GEMM: male/female = xo @ Wc^T  (K=2048, fp32 out)
    gemm3_dual<<<dim3(D_OUT / 128, B_DIM / 128), 256, 0, stream>>>(
        xo_hi, xo_lo,
        Wc_hi, Wc_lo,
        Wc_hi + (size_t)D_OUT * D_IN, Wc_lo + (size_t)D_OUT * D_IN,
        male, female, B_DIM, D_OUT, D_IN);

    // 6. sigmoid phase-lock blend (fp32 out)
    combine_kernel<<<B_DIM, 256, 0, stream>>>(male, female, out);
}

// Round 10
// 515.949 us; speedup vs baseline: 1.4506x; 1.0201x over previous
//
#include <hip/hip_runtime.h>
#include <hip/hip_bf16.h>
#include <math.h>

#define B_DIM 4096
#define D_IN  2048
#define D_HID 3584
#define D_OUT 2048

typedef __bf16 bf16;
typedef float  floatx4 __attribute__((ext_vector_type(4)));
typedef bf16   bf16x8  __attribute__((ext_vector_type(8)));
typedef bf16   bf16x4  __attribute__((ext_vector_type(4)));

typedef __attribute__((address_space(1))) const void* gptr1;
typedef __attribute__((address_space(3))) void*       lptr3;

__device__ __forceinline__ void load_lds16(const void* g, void* l) {
    __builtin_amdgcn_global_load_lds((gptr1)g, (lptr3)l, 16, 0, 0);
}

struct HL { bf16 h, l; };
__device__ __forceinline__ HL split2(float v) {
    HL r;
    r.h = (bf16)v;
    r.l = (bf16)(v - (float)r.h);
    return r;
}

// ---------------------------------------------------------------------------
// Vesica (fp32 in): x_overlap = x * (1 + relu(1 - |dist - 1|)); emit bf16 hi/lo
// ---------------------------------------------------------------------------
__global__ __launch_bounds__(256) void vesica_kernel(const float* __restrict__ x,
                                                     bf16* __restrict__ xh,
                                                     bf16* __restrict__ xl) {
    const int b  = blockIdx.x;
    const int bp = (b == 0) ? (B_DIM - 1) : (b - 1);
    const int t  = threadIdx.x;

    const floatx4* xr = (const floatx4*)(x + (size_t)b  * D_IN);
    const floatx4* pr = (const floatx4*)(x + (size_t)bp * D_IN);
    const floatx4 v0 = xr[t * 2], v1 = xr[t * 2 + 1];
    const floatx4 p0 = pr[t * 2], p1 = pr[t * 2 + 1];

    float s = 0.f;
#pragma unroll
    for (int j = 0; j < 4; ++j) {
        const float d0 = v0[j] - p0[j], d1 = v1[j] - p1[j];
        s += d0 * d0 + d1 * d1;
    }
#pragma unroll
    for (int off = 32; off > 0; off >>= 1) s += __shfl_down(s, off, 64);

    __shared__ float red[4];
    const int wave = t >> 6, lane = t & 63;
    if (lane == 0) red[wave] = s;
    __syncthreads();
    const float dist = sqrtf(red[0] + red[1] + red[2] + red[3]);
    const float sc   = 1.f + fmaxf(0.f, 1.f - fabsf(dist - 1.f));

    bf16x8 h, l;
#pragma unroll
    for (int j = 0; j < 4; ++j) {
        const HL a  = split2(v0[j] * sc);
        const HL b2 = split2(v1[j] * sc);
        h[j] = a.h;      l[j] = a.l;
        h[4 + j] = b2.h; l[4 + j] = b2.l;
    }
    ((bf16x8*)(xh + (size_t)b * D_IN))[t] = h;
    ((bf16x8*)(xl + (size_t)b * D_IN))[t] = l;
}

// ---------------------------------------------------------------------------
// Split fp32 weight array into bf16 hi/lo.
// ---------------------------------------------------------------------------
__global__ __launch_bounds__(256) void split_kernel(const float* __restrict__ w,
                                                    bf16* __restrict__ wh,
                                                    bf16* __restrict__ wl) {
    const size_t i = (size_t)blockIdx.x * 256 + threadIdx.x;
    const floatx4 a = ((const floatx4*)w)[i * 2];
    const floatx4 b = ((const floatx4*)w)[i * 2 + 1];
    bf16x8 h, l;
#pragma unroll
    for (int j = 0; j < 4; ++j) {
        const HL u = split2(a[j]);
        const HL v = split2(b[j]);
        h[j] = u.h;     l[j] = u.l;
        h[4 + j] = v.h; l[4 + j] = v.l;
    }
    ((bf16x8*)wh)[i] = h;
    ((bf16x8*)wl)[i] = l;
}

// ---------------------------------------------------------------------------
// Flip W_female [2048,3584] along axis 1, split into bf16 hi/lo.
// ---------------------------------------------------------------------------
__global__ __launch_bounds__(256) void flipsplit_kernel(const float* __restrict__ w,
                                                        bf16* __restrict__ wh,
                                                        bf16* __restrict__ wl) {
    const int i = blockIdx.x * 256 + threadIdx.x;
    const int o = i / 448;
    const int g = i - o * 448;
    const float* src = w + (size_t)o * 3584 + (size_t)(447 - g) * 8;
    const floatx4 a = ((const floatx4*)src)[0];
    const floatx4 b = ((const floatx4*)src)[1];
    bf16x8 h, l;
#pragma unroll
    for (int j = 0; j < 4; ++j) {
        const HL u = split2(b[3 - j]);   // out[0..3] = src[7..4]
        const HL v = split2(a[3 - j]);   // out[4..7] = src[3..0]
        h[j] = u.h;     l[j] = u.l;
        h[4 + j] = v.h; l[4 + j] = v.l;
    }
    ((bf16x8*)wh)[(size_t)o * 448 + g] = h;
    ((bf16x8*)wl)[(size_t)o * 448 + g] = l;
}

// ---------------------------------------------------------------------------
// Transpose + phase-scale + split: WflT[d,h] = P(h) * Wfl[h,d], bf16 hi/lo.
// P(h) = cos/sin(2pi*(h>>9)/7) for h%512 in {0,1}, else 1. 64x64 LDS tile.
// ---------------------------------------------------------------------------
__global__ __launch_bounds__(256) void tsplit_kernel(const float* __restrict__ w,
                                                     bf16* __restrict__ th,
                                                     bf16* __restrict__ tl) {
    __shared__ float tile[64][65];
    const int d0 = blockIdx.x * 64;   // 32 tiles along d
    const int h0 = blockIdx.y * 64;   // 56 tiles along h
    const int t  = threadIdx.x;
    const int r  = t >> 4;            // 0..15
    const int cg = (t & 15) << 2;     // 0..60

#pragma unroll
    for (int i = 0; i < 4; ++i) {
        const int hr = r + i * 16;
        const floatx4 v = *(const floatx4*)&w[(size_t)(h0 + hr) * 2048 + d0 + cg];
        tile[hr][cg]     = v[0];
        tile[hr][cg + 1] = v[1];
        tile[hr][cg + 2] = v[2];
        tile[hr][cg + 3] = v[3];
    }
    __syncthreads();

    float pm[4];
#pragma unroll
    for (int j = 0; j < 4; ++j) {
        const int h  = h0 + cg + j;
        const int hm = h & 511;
        float p = 1.f;
        if (hm < 2) {
            const float ph = 0.8975979010256552f * (float)(h >> 9); // 2pi/7*c
            p = (hm == 0) ? cosf(ph) : sinf(ph);
        }
        pm[j] = p;
    }

#pragma unroll
    for (int i = 0; i < 4; ++i) {
        const int dr = r + i * 16;
        bf16x4 hh, ll;
#pragma unroll
        for (int j = 0; j < 4; ++j) {
            const HL u = split2(tile[cg + j][dr] * pm[j]);
            hh[j] = u.h;
            ll[j] = u.l;
        }
        const size_t o = (size_t)(d0 + dr) * 3584 + h0 + cg;
        *(bf16x4*)&th[o] = hh;
        *(bf16x4*)&tl[o] = ll;
    }
}

// ---------------------------------------------------------------------------
// Single bf16x3 GEMM, C = A @ B^T, bf16 hi/lo out. 128x128 tile, BK=64:
// 96 MFMA per wave per barrier-pair (dual-level amortization), 64 KB LDS,
// 2 blocks/CU (128 KB <= 160). Used for Wc = Wcat @ WflT^T.
// ---------------------------------------------------------------------------
__global__ __launch_bounds__(256, 2) void gemm3_single(const bf16* __restrict__ Ah,
                                                       const bf16* __restrict__ Al,
                                                       const bf16* __restrict__ Bh,
                                                       const bf16* __restrict__ Bl,
                                                       bf16* __restrict__ C0,
                                                       bf16* __restrict__ C1,
                                                       int M, int N, int K) {
    __shared__ bf16 sAh[128 * 64], sAl[128 * 64];
    __shared__ bf16 sBh[128 * 64], sBl[128 * 64];

    const int tid  = threadIdx.x;
    const int wave = tid >> 6;
    const int lane = tid & 63;
    const int m0   = blockIdx.y * 128;
    const int n0   = blockIdx.x * 128;
    const int wm   = wave & 1;
    const int wn   = wave >> 1;

    floatx4 acc[4][4];
#pragma unroll
    for (int i = 0; i < 4; ++i)
#pragma unroll
        for (int j = 0; j < 4; ++j) acc[i][j] = (floatx4){0.f, 0.f, 0.f, 0.f};

    const int lr  = lane & 15;
    const int cc8 = (lane >> 4) << 3;

    for (int kt = 0; kt < K; kt += 64) {
        // each tile: 128 rows x 64 cols = 1024 16B-chunks -> 4 passes x 256 thr
#pragma unroll
        for (int i = 0; i < 4; ++i) {
            const int q = ((i * 4 + wave) << 6) + lane;   // 0..1023
            const int r = q >> 3, c = q & 7, e = q << 3;  // row, chunk, elem
            const size_t ga = (size_t)(m0 + r) * K + kt + c * 8;
            const size_t gb = (size_t)(n0 + r) * K + kt + c * 8;
            load_lds16(&Ah[ga], &sAh[e]);
            load_lds16(&Al[ga], &sAl[e]);
            load_lds16(&Bh[gb], &sBh[e]);
            load_lds16(&Bl[gb], &sBl[e]);
        }
        __syncthreads();

#pragma unroll
        for (int ks = 0; ks < 2; ++ks) {
            const int ko = (ks << 5) + cc8;
            bf16x8 ah[4], al[4], bh[4], bl[4];
#pragma unroll
            for (int mi = 0; mi < 4; ++mi) {
                const int off = ((wm * 64 + mi * 16 + lr) << 6) + ko;
                ah[mi] = *(const bf16x8*)&sAh[off];
                al[mi] = *(const bf16x8*)&sAl[off];
            }
#pragma unroll
            for (int ni = 0; ni < 4; ++ni) {
                const int off = ((wn * 64 + ni * 16 + lr) << 6) + ko;
                bh[ni] = *(const bf16x8*)&sBh[off];
                bl[ni] = *(const bf16x8*)&sBl[off];
            }

#pragma unroll
            for (int mi = 0; mi < 4; ++mi)
#pragma unroll
                for (int ni = 0; ni < 4; ++ni) {
                    acc[mi][ni] = __builtin_amdgcn_mfma_f32_16x16x32_bf16(
                        ah[mi], bh[ni], acc[mi][ni], 0, 0, 0);
                    acc[mi][ni] = __builtin_amdgcn_mfma_f32_16x16x32_bf16(
                        al[mi], bh[ni], acc[mi][ni], 0, 0, 0);
                    acc[mi][ni] = __builtin_amdgcn_mfma_f32_16x16x32_bf16(
                        ah[mi], bl[ni], acc[mi][ni], 0, 0, 0);
                }
        }
        __syncthreads();
    }

    const int rq = (lane >> 4) << 2;
    const int cl = lane & 15;
#pragma unroll
    for (int mi = 0; mi < 4; ++mi) {
#pragma unroll
        for (int ni = 0; ni < 4; ++ni) {
            const int col = n0 + wn * 64 + ni * 16 + cl;
#pragma unroll
            for (int r = 0; r < 4; ++r) {
                const int row = m0 + wm * 64 + mi * 16 + rq + r;
                const size_t idx = (size_t)row * N + col;
                const HL u = split2(acc[mi][ni][r]);
                C0[idx] = u.h;
                C1[idx] = u.l;
            }
        }
    }
}

// ---------------------------------------------------------------------------
// Dual GEMM (bf16x3): male = xo @ Wcm^T, female = xo @ Wcf^T in ONE kernel —
// A-tiles staged once for both products. 6 LDS tiles (48 KB), fp32 out.
// ---------------------------------------------------------------------------
__global__ __launch_bounds__(256, 2) void gemm3_dual(const bf16* __restrict__ Ah,
                                                     const bf16* __restrict__ Al,
                                                     const bf16* __restrict__ Bmh,
                                                     const bf16* __restrict__ Bml,
                                                     const bf16* __restrict__ Bfh,
                                                     const bf16* __restrict__ Bfl,
                                                     float* __restrict__ Cm,
                                                     float* __restrict__ Cf,
                                                     int M, int N, int K) {
    __shared__ bf16 sAh[4096], sAl[4096];
    __shared__ bf16 sMh[4096], sMl[4096];
    __shared__ bf16 sFh[4096], sFl[4096];

    const int tid  = threadIdx.x;
    const int wave = tid >> 6;
    const int lane = tid & 63;
    const int m0   = blockIdx.y * 128;
    const int n0   = blockIdx.x * 128;
    const int wm   = wave & 1;
    const int wn   = wave >> 1;

    floatx4 am[4][4], af[4][4];
#pragma unroll
    for (int i = 0; i < 4; ++i)
#pragma unroll
        for (int j = 0; j < 4; ++j) {
            am[i][j] = (floatx4){0.f, 0.f, 0.f, 0.f};
            af[i][j] = (floatx4){0.f, 0.f, 0.f, 0.f};
        }

    const int lr  = lane & 15;
    const int cc8 = (lane >> 4) << 3;

    for (int kt = 0; kt < K; kt += 32) {
#pragma unroll
        for (int i = 0; i < 2; ++i) {
            const int q = ((i * 4 + wave) << 6) + lane;
            const int r = q >> 2, c = q & 3, e = q << 3;
            const size_t ga = (size_t)(m0 + r) * K + kt + c * 8;
            const size_t gb = (size_t)(n0 + r) * K + kt + c * 8;
            load_lds16(&Ah[ga],  &sAh[e]);
            load_lds16(&Al[ga],  &sAl[e]);
            load_lds16(&Bmh[gb], &sMh[e]);
            load_lds16(&Bml[gb], &sMl[e]);
            load_lds16(&Bfh[gb], &sFh[e]);
            load_lds16(&Bfl[gb], &sFl[e]);
        }
        __syncthreads();

        bf16x8 ah[4], al[4];
#pragma unroll
        for (int mi = 0; mi < 4; ++mi) {
            const int off = ((wm * 64 + mi * 16 + lr) << 5) + cc8;
            ah[mi] = *(const bf16x8*)&sAh[off];
            al[mi] = *(const bf16x8*)&sAl[off];
        }
#pragma unroll
        for (int ni = 0; ni < 4; ++ni) {
            const int off = ((wn * 64 + ni * 16 + lr) << 5) + cc8;
            const bf16x8 mh = *(const bf16x8*)&sMh[off];
            const bf16x8 ml = *(const bf16x8*)&sMl[off];
            const bf16x8 fh = *(const bf16x8*)&sFh[off];
            const bf16x8 fl = *(const bf16x8*)&sFl[off];
#pragma unroll
            for (int mi = 0; mi < 4; ++mi) {
                am[mi][ni] = __builtin_amdgcn_mfma_f32_16x16x32_bf16(
                    ah[mi], mh, am[mi][ni], 0, 0, 0);
                am[mi][ni] = __builtin_amdgcn_mfma_f32_16x16x32_bf16(
                    al[mi], mh, am[mi][ni], 0, 0, 0);
                am[mi][ni] = __builtin_amdgcn_mfma_f32_16x16x32_bf16(
                    ah[mi], ml, am[mi][ni], 0, 0, 0);
                af[mi][ni] = __builtin_amdgcn_mfma_f32_16x16x32_bf16(
                    ah[mi], fh, af[mi][ni], 0, 0, 0);
                af[mi][ni] = __builtin_amdgcn_mfma_f32_16x16x32_bf16(
                    al[mi], fh, af[mi][ni], 0, 0, 0);
                af[mi][ni] = __builtin_amdgcn_mfma_f32_16x16x32_bf16(
                    ah[mi], fl, af[mi][ni], 0, 0, 0);
            }
        }
        __syncthreads();
    }

    const int rq = (lane >> 4) << 2;
    const int cl = lane & 15;
#pragma unroll
    for (int mi = 0; mi < 4; ++mi) {
#pragma unroll
        for (int ni = 0; ni < 4; ++ni) {
            const int col = n0 + wn * 64 + ni * 16 + cl;
#pragma unroll
            for (int r = 0; r < 4; ++r) {
                const int row = m0 + wm * 64 + mi * 16 + rq + r;
                const size_t idx = (size_t)row * N + col;
                Cm[idx] = am[mi][ni][r];
                Cf[idx] = af[mi][ni][r];
            }
        }
    }
}

// ---------------------------------------------------------------------------
// Combine: phase_lock = sigmoid(male . female); out = pl*male + (1-pl)*female
// ---------------------------------------------------------------------------
__global__ __launch_bounds__(256) void combine_kernel(const float* __restrict__ male,
                                                      const float* __restrict__ female,
                                                      float* __restrict__ out) {
    const int b = blockIdx.x;
    const int t = threadIdx.x;

    const floatx4* m4 = (const floatx4*)(male   + (size_t)b * D_OUT);
    const floatx4* f4 = (const floatx4*)(female + (size_t)b * D_OUT);
    const floatx4 mv0 = m4[t * 2], mv1 = m4[t * 2 + 1];
    const floatx4 fv0 = f4[t * 2], fv1 = f4[t * 2 + 1];

    float s = 0.f;
#pragma unroll
    for (int j = 0; j < 4; ++j) s += mv0[j] * fv0[j] + mv1[j] * fv1[j];
#pragma unroll
    for (int off = 32; off > 0; off >>= 1) s += __shfl_down(s, off, 64);

    __shared__ float red[4];
    const int wave = t >> 6, lane = t & 63;
    if (lane == 0) red[wave] = s;
    __syncthreads();
    const float dot = red[0] + red[1] + red[2] + red[3];
    const float pl  = 1.f / (1.f + expf(-dot));

    floatx4 o0, o1;
#pragma unroll
    for (int j = 0; j < 4; ++j) {
        o0[j] = pl * mv0[j] + (1.f - pl) * fv0[j];
        o1[j] = pl * mv1[j] + (1.f - pl) * fv1[j];
    }
    floatx4* o4 = (floatx4*)(out + (size_t)b * D_OUT);
    o4[t * 2]     = o0;
    o4[t * 2 + 1] = o1;
}

// ---------------------------------------------------------------------------
// Pipeline:  male = xo @ (Wm P Wfl)^T,  female = xo @ (Wfe_flip P Wfl)^T
// ---------------------------------------------------------------------------
extern "C" void kernel_launch(void* const* d_in, const int* in_sizes, int n_in,
                              void* d_out, int out_size, void* d_ws, size_t ws_size,
                              hipStream_t stream) {
    const float* x   = (const float*)d_in[0];
    const float* Wfl = (const float*)d_in[1]; // [7,512,2048] == [3584,2048]
    const float* Wm  = (const float*)d_in[2]; // [2048,3584]
    const float* Wfe = (const float*)d_in[3]; // [2048,3584]
    float* out = (float*)d_out;
    (void)in_sizes; (void)n_in; (void)out_size; (void)ws_size;

    char* ws = (char*)d_ws;
    bf16*  xo_hi   = (bf16*)(ws);                    // 4096x2048 = 16,777,216
    bf16*  xo_lo   = (bf16*)(ws + 16777216);         // 16,777,216
    bf16*  Wc_hi   = (bf16*)(ws + 33554432);         // 4096x2048 = 16,777,216
    bf16*  Wc_lo   = (bf16*)(ws + 50331648);         // 16,777,216 -> 67,108,864
    // overlay phase A (dead after gemm3_single):
    bf16*  WflT_hi = (bf16*)(ws + 67108864);         // 2048x3584 = 14,680,064
    bf16*  WflT_lo = (bf16*)(ws + 81788928);         // -> 96,468,992
    bf16*  Wcat_hi = (bf16*)(ws + 96468992);         // 4096x3584 = 29,360,128
    bf16*  Wcat_lo = (bf16*)(ws + 125829120);        // -> 155,189,248
    // overlay phase B (after gemm3_single):
    float* male    = (float*)(ws + 67108864);        // 4096x2048 f32 = 33,554,432
    float* female  = (float*)(ws + 100663296);       // -> 134,217,728

    // 1. vesica scaling (fp32 -> bf16 hi/lo)
    vesica_kernel<<<B_DIM, 256, 0, stream>>>(x, xo_hi, xo_lo);

    // 2. transpose + phase-scale + split Wfl -> WflT [2048, 3584]
    tsplit_kernel<<<dim3(D_IN / 64, D_HID / 64), 256, 0, stream>>>(Wfl, WflT_hi, WflT_lo);

    // 3. Wcat = [Wm ; Wfe_flip], bf16 hi/lo [4096, 3584]
    split_kernel<<<(D_OUT * D_HID / 8) / 256, 256, 0, stream>>>(Wm, Wcat_hi, Wcat_lo);
    flipsplit_kernel<<<(D_OUT * (D_HID / 8)) / 256, 256, 0, stream>>>(
        Wfe, Wcat_hi + (size_t)D_OUT * D_HID, Wcat_lo + (size_t)D_OUT * D_HID);

    // 4. weight combine: Wc[4096,2048] = Wcat @ WflT^T  (K=3584, BK=64)
    gemm3_single<<<dim3(D_IN / 128, (2 * D_OUT) / 128), 256, 0, stream>>>(
        Wcat_hi, Wcat_lo, WflT_hi, WflT_lo, Wc_hi, Wc_lo,
        2 * D_OUT, D_IN, D_HID);

    // 5. main dual GEMM: male/female = xo @ Wc^T  (K=2048, fp32 out)
    gemm3_dual<<<dim3(D_OUT / 128, B_DIM / 128), 256, 0, stream>>>(
        xo_hi, xo_lo,
        Wc_hi, Wc_lo,
        Wc_hi + (size_t)D_OUT * D_IN, Wc_lo + (size_t)D_OUT * D_IN,
        male, female, B_DIM, D_OUT, D_IN);

    // 6. sigmoid phase-lock blend (fp32 out)
    combine_kernel<<<B_DIM, 256, 0, stream>>>(male, female, out);
}